// Round 8
// baseline (223.315 us; speedup 1.0000x reference)
//
#include <hip/hip_runtime.h>
#include <math.h>

// Problem constants (fixed by setup_inputs)
constexpr int B_   = 2;
constexpr int C_   = 64;
constexpr int H_   = 128;
constexpr int W_   = 128;
constexpr int HW_  = H_ * W_;
constexpr int DG_  = 16;   // deformable groups
constexpr int KK_  = 9;    // 3x3 taps
constexpr int CG_  = 4;    // channels per group = C/DG
constexpr int OFFC_ = 3 * KK_ * DG_;  // 432
constexpr int R_   = C_ * KK_;        // 576 reduction length
constexpr int WP_  = 130;             // padded width/height
constexpr int HWP_ = WP_ * WP_;       // 16900 padded pixels

typedef _Float16 half8 __attribute__((ext_vector_type(8)));  // 8 f16 = 4 VGPR
typedef _Float16 half4 __attribute__((ext_vector_type(4)));  // 8-byte load/store
typedef float floatx4 __attribute__((ext_vector_type(4)));   // MFMA acc

// Async global->LDS DMA, 16 B per lane. LDS dest is wave-uniform base +
// lane*16 (m104); every call site passes exactly that shape.
__device__ __forceinline__ void gl_lds16(const _Float16* g, _Float16* l)
{
    __builtin_amdgcn_global_load_lds(
        (const __attribute__((address_space(1))) void*)g,
        (__attribute__((address_space(3))) void*)l, 16, 0, 0);
}

// Fragment-major A staging: LDS chunk c (16 B) holds the data fragment
// (mf = c>>6) needs at lane (c&63): global f16 index within the K-slice.
// Reader then does afr[mf] = lds[base + lane*16 + mf*1024] -> addresses
// linear in lane -> conflict-free ds_read_b128.
__device__ __forceinline__ int afrag_src(int c)
{
    const int cmf = c >> 6, cq = (c >> 4) & 3, cl = c & 15;
    return (cmf * 16 + cl) * 32 + cq * 8;
}

// ---------------------------------------------------------------------------
// Generic MFMA A-operand prep: wA[(t*CH+h)*OC + oc][j] = f16(w[oc][(h*32+j)*9+t])
// ---------------------------------------------------------------------------
template <int OC, int CIN>
__global__ __launch_bounds__(256) void prep_wA_k(
    const float* __restrict__ w, _Float16* __restrict__ wA)
{
    constexpr int CH = CIN / 32;
    const int j = blockIdx.x * 256 + threadIdx.x;   // slab*OC*32 + oc*32 + jj
    if (j >= 9 * CH * OC * 32) return;
    const int slab = j / (OC * 32);
    const int rem  = j - slab * (OC * 32);
    const int oc   = rem >> 5;
    const int jj   = rem & 31;
    const int t    = slab / CH;
    const int h    = slab - t * CH;
    const int ic   = h * 32 + jj;
    wA[j] = (_Float16)w[(size_t)oc * (CIN * 9) + ic * 9 + t];
}

// ---------------------------------------------------------------------------
// Einsum A-operand prep: r = k*64 + gc (gc = g*4+c).  18 slabs of 32.
// ---------------------------------------------------------------------------
__global__ __launch_bounds__(256) void prep_wkA_k(
    const float* __restrict__ wk, _Float16* __restrict__ wkA)
{
    const int j = blockIdx.x * 256 + threadIdx.x;   // s*2048 + oc*32 + jj
    if (j >= 18 * 64 * 32) return;
    const int s   = j >> 11;
    const int rem = j & 2047;
    const int oc  = rem >> 5;
    const int jj  = rem & 31;
    const int k   = s >> 1;
    const int gc  = (s & 1) * 32 + jj;
    wkA[j] = (_Float16)wk[(size_t)oc * R_ + gc * 9 + k];
}

// ---------------------------------------------------------------------------
// NCHW fp32 -> PADDED slab-split f16: out[(c/32)*B + b][y+1][x+1][32].
// ---------------------------------------------------------------------------
template <int CC>
__global__ __launch_bounds__(256) void nchw2slabpad_f16_k(
    const float* __restrict__ in, _Float16* __restrict__ outh)
{
    const int pix = blockIdx.x * 256 + threadIdx.x;
    const int b   = blockIdx.y;
    const int yp  = pix >> 7;
    const int xp  = pix & (W_ - 1);
    const float* ib = in + (size_t)b * CC * HW_ + pix;
#pragma unroll
    for (int c0 = 0; c0 < CC; c0 += 8) {
        half8 v;
#pragma unroll
        for (int j = 0; j < 8; ++j)
            v[j] = (_Float16)ib[(size_t)(c0 + j) * HW_];
        const int slab = c0 >> 5;
        *(half8*)&outh[((size_t)(slab * B_ + b) * HWP_
                        + (size_t)(yp + 1) * WP_ + (xp + 1)) * 32 + (c0 & 31)] = v;
    }
}

// ---------------------------------------------------------------------------
// NCHW fp32 -> per-group planes f16: xg[((b*DG+g)*HW + pix)*4 + c].
// ---------------------------------------------------------------------------
__global__ __launch_bounds__(256) void nchw2gx_f16_k(
    const float* __restrict__ in, _Float16* __restrict__ outh)
{
    const int pix = blockIdx.x * 256 + threadIdx.x;
    const int b   = blockIdx.y;
    const float* ib = in + (size_t)b * C_ * HW_ + pix;
#pragma unroll
    for (int g = 0; g < DG_; ++g) {
        half4 v;
#pragma unroll
        for (int c = 0; c < 4; ++c)
            v[c] = (_Float16)ib[(size_t)(g * 4 + c) * HW_];
        *(half4*)&outh[((size_t)(b * DG_ + g) * HW_ + pix) * 4] = v;
    }
}

// ---------------------------------------------------------------------------
// Conv1 (128 -> 64) via f16 MFMA. Wave tile = 64 oc x 16 px (mf=4).
// 2 K-steps per barrier phase (36 steps -> 18 phases). A dbuf = 16 KB.
// ---------------------------------------------------------------------------
__global__ __launch_bounds__(256, 2) void conv1_mfma_k(
    const _Float16* __restrict__ inp, const _Float16* __restrict__ wA,
    const float* __restrict__ bias, _Float16* __restrict__ outp)
{
    __shared__ __align__(16) _Float16 Asm[2 * 4096];   // 16 KB

    const int tid  = threadIdx.x;
    const int lane = tid & 63;
    const int wv   = tid >> 6;
    const int l15  = lane & 15;
    const int quad = lane >> 4;

    const int zx   = blockIdx.x;          // (b*H + y)*2 + half64
    const int row  = zx >> 1;
    const int b    = row >> 7;
    const int y    = row & 127;
    const int px0  = (zx & 1) * 64 + wv * 16;

    const int sA = afrag_src(tid);        // global f16 offset for my chunk

    floatx4 acc[4];
#pragma unroll
    for (int mf = 0; mf < 4; ++mf)
        acc[mf] = (floatx4){0.f, 0.f, 0.f, 0.f};

    half8 Bf[2][2];                       // [phase buf][slice]

    // prologue: stage phase 0 (ks=0,1 -> t=0, h=0,1), load B ks=0,1
    gl_lds16(wA + 0 * 2048 + sA, Asm + 0 * 2048 + tid * 8);
    gl_lds16(wA + 1 * 2048 + sA, Asm + 1 * 2048 + tid * 8);
#pragma unroll
    for (int j = 0; j < 2; ++j)
        Bf[0][j] = *(const half8*)&inp[
            ((size_t)(j * B_ + b) * HWP_ + (size_t)(y + 0) * WP_
             + (px0 + l15 + 0)) * 32 + quad * 8];
    __syncthreads();

#pragma unroll
    for (int p = 0; p < 18; ++p) {        // phase p covers ks = 2p, 2p+1
        const int cur = p & 1, nxt = cur ^ 1;
        if (p < 17) {
            const int ks0 = 2 * p + 2;    // first slice of next phase
            const int t = ks0 >> 2;       // CH=4: ks = t*4 + h
            const int h0 = ks0 & 3;       // and h0+1 for the second slice
            const int dy = t / 3, dx = t % 3;
#pragma unroll
            for (int j = 0; j < 2; ++j) {
                gl_lds16(wA + (size_t)(ks0 + j) * 2048 + sA,
                         Asm + (nxt * 2 + j) * 2048 + tid * 8);
                Bf[nxt][j] = *(const half8*)&inp[
                    ((size_t)((h0 + j) * B_ + b) * HWP_ + (size_t)(y + dy) * WP_
                     + (px0 + l15 + dx)) * 32 + quad * 8];
            }
        }
#pragma unroll
        for (int j = 0; j < 2; ++j) {
            const _Float16* abase = Asm + (cur * 2 + j) * 2048 + lane * 8;
#pragma unroll
            for (int mf = 0; mf < 4; ++mf) {
                const half8 afr = *(const half8*)&abase[mf * 512];
                acc[mf] = __builtin_amdgcn_mfma_f32_16x16x32_f16(afr, Bf[cur][j], acc[mf], 0, 0, 0);
            }
        }
        __syncthreads();   // drains vmcnt: next phase's A/B landed
    }

    // epilogue: leaky ReLU, padded slab-split f16 store (8 B/lane x 4 tiles)
#pragma unroll
    for (int mf = 0; mf < 4; ++mf) {
        const int oc4 = mf * 16 + quad * 4;        // first of 4 output chans
        const float4 b4 = *(const float4*)&bias[oc4];
        half4 v4;
#pragma unroll
        for (int reg = 0; reg < 4; ++reg) {
            float r = acc[mf][reg] + ((const float*)&b4)[reg];
            r = (r >= 0.f) ? r : 0.1f * r;
            v4[reg] = (_Float16)r;
        }
        *(half4*)&outp[((size_t)((oc4 >> 5) * B_ + b) * HWP_
                        + (size_t)(y + 1) * WP_ + (px0 + l15 + 1)) * 32 + (oc4 & 31)] = v4;
    }
}

// ---------------------------------------------------------------------------
// Conv2 (64 -> 64) via f16 MFMA. Wave tile = 64 oc x 16 px (mf=4).
// FULL A preload (72 KB LDS), then barrier-free 18-step K-loop.
// ---------------------------------------------------------------------------
__global__ __launch_bounds__(256, 2) void conv2_mfma_k(
    const _Float16* __restrict__ inp, const _Float16* __restrict__ wA,
    const float* __restrict__ bias, _Float16* __restrict__ outp)
{
    __shared__ __align__(16) _Float16 Asm[18 * 2048];   // 73728 B

    const int tid  = threadIdx.x;
    const int lane = tid & 63;
    const int wv   = tid >> 6;
    const int l15  = lane & 15;
    const int quad = lane >> 4;

    const int zx   = blockIdx.x;          // (b*H + y)*2 + half64
    const int row  = zx >> 1;
    const int b    = row >> 7;
    const int y    = row & 127;
    const int px0  = (zx & 1) * 64 + wv * 16;

    const int sA = afrag_src(tid);

    // full preload: 18 slabs x 4 KB
#pragma unroll
    for (int s = 0; s < 18; ++s)
        gl_lds16(wA + (size_t)s * 2048 + sA, Asm + s * 2048 + tid * 8);

    floatx4 acc[4];
#pragma unroll
    for (int mf = 0; mf < 4; ++mf)
        acc[mf] = (floatx4){0.f, 0.f, 0.f, 0.f};

    half8 Bf[2];
    Bf[0] = *(const half8*)&inp[
        ((size_t)(0 * B_ + b) * HWP_ + (size_t)(y + 0) * WP_
         + (px0 + l15 + 0)) * 32 + quad * 8];
    __syncthreads();   // preload (all waves) visible

#pragma unroll
    for (int ks = 0; ks < 18; ++ks) {     // ks = t*2 + h  (CH=2)
        const int cur = ks & 1, nxt = cur ^ 1;
        if (ks < 17) {
            const int ks1 = ks + 1;
            const int t = ks1 >> 1, h = ks1 & 1;
            const int dy = t / 3, dx = t % 3;
            Bf[nxt] = *(const half8*)&inp[
                ((size_t)(h * B_ + b) * HWP_ + (size_t)(y + dy) * WP_
                 + (px0 + l15 + dx)) * 32 + quad * 8];
        }
        const _Float16* abase = Asm + ks * 2048 + lane * 8;
#pragma unroll
        for (int mf = 0; mf < 4; ++mf) {
            const half8 afr = *(const half8*)&abase[mf * 512];
            acc[mf] = __builtin_amdgcn_mfma_f32_16x16x32_f16(afr, Bf[cur], acc[mf], 0, 0, 0);
        }
    }

    // epilogue: leaky ReLU, padded slab-split f16 store
#pragma unroll
    for (int mf = 0; mf < 4; ++mf) {
        const int oc4 = mf * 16 + quad * 4;
        const float4 b4 = *(const float4*)&bias[oc4];
        half4 v4;
#pragma unroll
        for (int reg = 0; reg < 4; ++reg) {
            float r = acc[mf][reg] + ((const float*)&b4)[reg];
            r = (r >= 0.f) ? r : 0.1f * r;
            v4[reg] = (_Float16)r;
        }
        *(half4*)&outp[((size_t)((oc4 >> 5) * B_ + b) * HWP_
                        + (size_t)(y + 1) * WP_ + (px0 + l15 + 1)) * 32 + (oc4 & 31)] = v4;
    }
}

// ---------------------------------------------------------------------------
// Conv3 via f16 MFMA implicit GEMM.
// v7: 64-px x 48-oc blocks; the K-loop touches ONLY LDS and registers.
//   - B working set for ALL 18 K-steps staged once: 24 planes (h,dy,quad)
//     x 68 px x 16 B = 26112 B. Per-quad-plane px records are 16 B at
//     16-B stride -> 16-lane groups read 256 B contiguous, conflict-free.
//   - A slices 0..11 staged to LDS (36864 B); slices 12..17 preloaded to
//     registers (18 half8). Total LDS 62976 B -> 2 blocks/CU.
//   - ONE barrier after the preload burst; the 18-step loop has zero
//     barriers and ZERO global loads -> no per-step L2 round-trip, the
//     serializer every previous conv3 variant shared.
// Grid (B*H*2, 9) = 4608 blocks. Epilogue tile (48x68 f16) aliases Smem.
// ---------------------------------------------------------------------------
__global__ __launch_bounds__(256, 2) void conv3_mfma_k(
    const _Float16* __restrict__ h2p, const _Float16* __restrict__ w3A,
    const float* __restrict__ bias, const float* __restrict__ flow,
    _Float16* __restrict__ omh)
{
    __shared__ __align__(16) _Float16 Smem[31488];   // 62976 B
    _Float16* Asm = Smem;                 // f16 [0, 18432): A slices 0..11
    _Float16* Bsm = Smem + 18432;         // f16 [18432, 31488): B planes
    _Float16* Lds = Smem;                 // epilogue alias (48 x 68 f16)

    const int tid  = threadIdx.x;
    const int lane = tid & 63;
    const int wv   = tid >> 6;       // wave id 0..3
    const int l15  = lane & 15;
    const int quad = lane >> 4;

    const int zx   = blockIdx.x;     // (b*H + y)*2 + half
    const int row  = zx >> 1;
    const int b    = row >> 7;
    const int y    = row & 127;
    const int px0b = (zx & 1) * 64;  // block pixel base
    const int pxw  = wv * 16;        // wave window within block
    const int m0   = blockIdx.y * 48;

    // ---- stage A slices 0..11: 12 x 192 = 2304 chunks = 9 exact rounds ----
#pragma unroll
    for (int r = 0; r < 9; ++r) {
        const int c  = r * 256 + tid;
        const int ks = c / 192;
        const int cl = c - ks * 192;
        const int cmf = cl >> 6, cq = (cl >> 4) & 3, ccl = cl & 15;
        gl_lds16(w3A + ((size_t)ks * OFFC_ + m0 + cmf * 16 + ccl) * 32 + cq * 8,
                 Asm + c * 8);
    }
    // ---- stage B: 24 planes x 68 px = 1632 chunks (7 rounds, tail mask) ----
#pragma unroll
    for (int r = 0; r < 7; ++r) {
        const int cb = r * 256 + tid;
        if (cb < 1632) {
            const int plane = cb / 68;
            const int pxl   = cb - plane * 68;
            const int h  = plane / 12;
            const int rm = plane - h * 12;
            const int dy = rm >> 2;
            const int q  = rm & 3;
            int col = px0b + pxl; if (col > 129) col = 129;
            gl_lds16(h2p + ((size_t)(h * B_ + b) * HWP_
                            + (size_t)(y + dy) * WP_ + col) * 32 + q * 8,
                     Bsm + cb * 8);
        }
    }
    // ---- A slices 12..17 direct to registers (drained by the barrier) ----
    half8 Areg[6][3];
#pragma unroll
    for (int s = 0; s < 6; ++s)
#pragma unroll
        for (int mf = 0; mf < 3; ++mf)
            Areg[s][mf] = *(const half8*)&w3A[
                ((size_t)(12 + s) * OFFC_ + m0 + mf * 16 + l15) * 32 + quad * 8];

    floatx4 acc[3];
#pragma unroll
    for (int mf = 0; mf < 3; ++mf)
        acc[mf] = (floatx4){0.f, 0.f, 0.f, 0.f};

    __syncthreads();   // single drain: all staging landed

    // ---- barrier-free, global-free K-loop ----
#pragma unroll
    for (int ks = 0; ks < 18; ++ks) {           // ks = t*2 + h
        const int t = ks >> 1, h = ks & 1;
        const int dy = t / 3, dx = t % 3;
        const half8 bfr = *(const half8*)&Bsm[
            ((((h * 3 + dy) << 2) + quad) * 68 + pxw + l15 + dx) * 8];
#pragma unroll
        for (int mf = 0; mf < 3; ++mf) {
            half8 afr;
            if (ks < 12)
                afr = *(const half8*)&Asm[ks * 1536 + mf * 512 + lane * 8];
            else
                afr = Areg[ks - 12][mf];
            acc[mf] = __builtin_amdgcn_mfma_f32_16x16x32_f16(afr, bfr, acc[mf], 0, 0, 0);
        }
    }
    __syncthreads();   // done reading Asm/Bsm; safe to alias Lds

    // ---- transform + stage to LDS (f16, 48 rows x 64 px, stride 68) ----
    const bool is_off = (blockIdx.y < 6);     // block-uniform: m0 < 288
    const int px = px0b + pxw + l15;
    float flY = 0.f, flX = 0.f;
    if (is_off) {
        flY = flow[(size_t)(b * 2 + 1) * HW_ + y * W_ + px]; // slot 0 (y)
        flX = flow[(size_t)(b * 2 + 0) * HW_ + y * W_ + px]; // slot 1 (x)
    }
#pragma unroll
    for (int mf = 0; mf < 3; ++mf) {
        const float4 b4 = *(const float4*)&bias[m0 + mf * 16 + quad * 4];
#pragma unroll
        for (int reg = 0; reg < 4; ++reg) {
            const int ocl = mf * 16 + quad * 4 + reg;   // 0..47
            float val = acc[mf][reg] + ((const float*)&b4)[reg];
            if (is_off) {                       // offset channels
                const int slot = reg & 1;       // 0 = y, 1 = x
                const float fl = slot ? flX : flY;
                const float e = __expf(2.f * val);      // tanh via exp
                val = 10.f * (1.f - __fdividef(2.f, e + 1.f)) + fl;
            } else {                            // mask channels: sigmoid
                val = __fdividef(1.f, 1.f + __expf(-val));
            }
            Lds[ocl * 68 + pxw + l15] = (_Float16)val;
        }
    }
    __syncthreads();   // LDS read-only hereafter

    // ---- contiguous f16 copy-out: 48 plane-rows x 64 px (3 x 256) ----
#pragma unroll
    for (int it = 0; it < 3; ++it) {
        const int j4 = it * 256 + tid;
        const int r  = j4 >> 4;          // 0..47
        const int c4 = j4 & 15;          // half4 col
        const int oc = m0 + r;
        int g, k, slot;
        if (oc < 2 * DG_ * KK_) {
            g = oc / 18;
            const int rem = oc - g * 18;
            k = rem >> 1;
            slot = rem & 1;
        } else {
            const int c = oc - 2 * DG_ * KK_;
            g = c / 9;
            k = c - g * 9;
            slot = 2;
        }
        const half4 hv = *(const half4*)&Lds[r * 68 + c4 * 4];
        *(half4*)&omh[((size_t)((b * DG_ * KK_ + g * KK_ + k) * 3 + slot)) * HW_
                      + y * W_ + px0b + c4 * 4] = hv;
    }
}

// ---------------------------------------------------------------------------
// Phase A: bilinear gather, PIXEL-MAJOR lanes. Thread = one pixel for a
// fixed (b,k); loops g=0..15 in registers.
// ---------------------------------------------------------------------------
__global__ __launch_bounds__(256) void gather_k(
    const _Float16* __restrict__ xg, const _Float16* __restrict__ omh,
    _Float16* __restrict__ valh)
{
    const int tid = threadIdx.x;
    const int pix = blockIdx.x * 256 + tid;
    const int zy  = blockIdx.y;               // b*9 + k
    const int b   = zy / KK_;
    const int k   = zy - b * KK_;
    const int yp  = pix >> 7;
    const int xp  = pix & (W_ - 1);
    const float fy = (float)(yp + (k / 3) - 1);
    const float fx = (float)(xp + (k % 3) - 1);

    half4 rec[16];
#pragma unroll
    for (int g = 0; g < DG_; ++g) {
        const size_t obase = ((size_t)((b * DG_ + g) * KK_ + k) * 3) * HW_ + pix;
        const float oy = (float)omh[obase];
        const float ox = (float)omh[obase + HW_];
        const float m  = (float)omh[obase + 2 * HW_];

        const float py = fy + oy;
        const float px = fx + ox;
        const float y0f = floorf(py);
        const float x0f = floorf(px);
        const float wy = py - y0f;
        const float wx = px - x0f;
        const int y0 = (int)y0f, x0 = (int)x0f;
        const int y1 = y0 + 1,  x1 = x0 + 1;
        const bool vy0 = ((unsigned)y0 < (unsigned)H_);
        const bool vy1 = ((unsigned)y1 < (unsigned)H_);
        const bool vx0 = ((unsigned)x0 < (unsigned)W_);
        const bool vx1 = ((unsigned)x1 < (unsigned)W_);
        const float w00 = vy0 && vx0 ? (1.f - wy) * (1.f - wx) : 0.f;
        const float w01 = vy0 && vx1 ? (1.f - wy) * wx         : 0.f;
        const float w10 = vy1 && vx0 ? wy * (1.f - wx)         : 0.f;
        const float w11 = vy1 && vx1 ? wy * wx                 : 0.f;
        const int i00 = (vy0 && vx0) ? y0 * W_ + x0 : 0;
        const int i01 = (vy0 && vx1) ? y0 * W_ + x1 : 0;
        const int i10 = (vy1 && vx0) ? y1 * W_ + x0 : 0;
        const int i11 = (vy1 && vx1) ? y1 * W_ + x1 : 0;

        const _Float16* xb = xg + (size_t)(b * DG_ + g) * HW_ * 4;
        const half4 p00 = *(const half4*)&xb[(size_t)i00 * 4];
        const half4 p01 = *(const half4*)&xb[(size_t)i01 * 4];
        const half4 p10 = *(const half4*)&xb[(size_t)i10 * 4];
        const half4 p11 = *(const half4*)&xb[(size_t)i11 * 4];

        half4 v4;
#pragma unroll
        for (int c = 0; c < CG_; ++c) {
            float v = w00 * (float)p00[c] + w01 * (float)p01[c]
                    + w10 * (float)p10[c] + w11 * (float)p11[c];
            v4[c] = (_Float16)(v * m);
        }
        rec[g] = v4;
    }

    // write slabs s = 2k (g 0..7) and 2k+1 (g 8..15): 64 B each, contiguous
    _Float16* r0 = &valh[((size_t)((2 * k) * B_ + b) * HW_ + pix) * 32];
    _Float16* r1 = &valh[((size_t)((2 * k + 1) * B_ + b) * HW_ + pix) * 32];
#pragma unroll
    for (int j = 0; j < 4; ++j) {
        half8 w0, w1;
#pragma unroll
        for (int c = 0; c < 4; ++c) {
            w0[c]     = rec[2 * j][c];
            w0[c + 4] = rec[2 * j + 1][c];
            w1[c]     = rec[8 + 2 * j][c];
            w1[c + 4] = rec[9 + 2 * j][c];
        }
        *(half8*)&r0[j * 8] = w0;
        *(half8*)&r1[j * 8] = w1;
    }
}

// ---------------------------------------------------------------------------
// Phase B: einsum via f16 MFMA. Wave = 16 px x 64 oc (mf=4).
// FULL A preload (72 KB), barrier-free 18-step loop, epilogue aliases A.
// ---------------------------------------------------------------------------
__global__ __launch_bounds__(256, 2) void einsum_mfma_k(
    const _Float16* __restrict__ valh, const _Float16* __restrict__ wkA,
    float* __restrict__ out)
{
    __shared__ __align__(16) _Float16 Smem[18 * 2048];  // 73728 B (union)
    float* Lds = (float*)Smem;                          // epilogue view

    const int tid  = threadIdx.x;
    const int lane = tid & 63;
    const int wv   = tid >> 6;
    const int l15  = lane & 15;
    const int quad = lane >> 4;

    const int pixg0 = blockIdx.x * 64 + wv * 16;    // global pixel (b*HW+pix)
    const int b     = pixg0 >> 14;
    const int pix0  = pixg0 & (HW_ - 1);

    const int sA = afrag_src(tid);

    // full preload: 18 slabs x 4 KB
#pragma unroll
    for (int s = 0; s < 18; ++s)
        gl_lds16(wkA + (size_t)s * 2048 + sA, Smem + s * 2048 + tid * 8);

    floatx4 acc[4];
#pragma unroll
    for (int mf = 0; mf < 4; ++mf)
        acc[mf] = (floatx4){0.f, 0.f, 0.f, 0.f};

    half8 Bf[2];
    Bf[0] = *(const half8*)&valh[((size_t)(0 * B_ + b) * HW_ + pix0 + l15) * 32 + quad * 8];
    __syncthreads();   // preload visible

#pragma unroll
    for (int s = 0; s < 18; ++s) {
        const int cur = s & 1, nxt = cur ^ 1;
        if (s < 17) {
            const int s1 = s + 1;
            Bf[nxt] = *(const half8*)&valh[
                ((size_t)(s1 * B_ + b) * HW_ + pix0 + l15) * 32 + quad * 8];
        }
        const _Float16* abase = Smem + s * 2048 + lane * 8;
#pragma unroll
        for (int mf = 0; mf < 4; ++mf) {
            const half8 afr = *(const half8*)&abase[mf * 512];
            acc[mf] = __builtin_amdgcn_mfma_f32_16x16x32_f16(afr, Bf[cur], acc[mf], 0, 0, 0);
        }
    }
    __syncthreads();   // all waves done reading A; safe to alias

    // ---- stage 64 oc x 64 px tile to LDS ----
    const int pxl = wv * 16 + l15;                  // 0..63 block-local pixel
#pragma unroll
    for (int mf = 0; mf < 4; ++mf)
#pragma unroll
        for (int reg = 0; reg < 4; ++reg)
            Lds[(mf * 16 + quad * 4 + reg) * 68 + pxl] = acc[mf][reg];
    __syncthreads();   // LDS read-only hereafter

    // ---- coalesced copy-out: 64 oc-rows x 64 px (16 float4 per row) ----
    const int pixb = blockIdx.x * 64 & (HW_ - 1);   // block-base pixel
#pragma unroll
    for (int it = 0; it < 4; ++it) {
        const int j4 = it * 256 + tid;
        const int r  = j4 >> 4;                     // oc 0..63
        const int c4 = j4 & 15;                     // float4 col
        float4 v;
        v.x = Lds[r * 68 + c4 * 4 + 0];
        v.y = Lds[r * 68 + c4 * 4 + 1];
        v.z = Lds[r * 68 + c4 * 4 + 2];
        v.w = Lds[r * 68 + c4 * 4 + 3];
        *(float4*)&out[((size_t)(b * C_ + r)) * HW_ + pixb + c4 * 4] = v;
    }
}

// ---------------------------------------------------------------------------
extern "C" void kernel_launch(void* const* d_in, const int* in_sizes, int n_in,
                              void* d_out, int out_size, void* d_ws, size_t ws_size,
                              hipStream_t stream)
{
    const float* x    = (const float*)d_in[0];
    const float* ef   = (const float*)d_in[1];
    const float* flow = (const float*)d_in[2];
    const float* w1   = (const float*)d_in[3];
    const float* b1   = (const float*)d_in[4];
    const float* w2   = (const float*)d_in[5];
    const float* b2   = (const float*)d_in[6];
    const float* w3   = (const float*)d_in[7];
    const float* b3   = (const float*)d_in[8];
    const float* wk   = (const float*)d_in[9];
    float* out = (float*)d_out;

    // Workspace (half slots):
    //   omh 14,155,776 | valh 18,874,368 | ef_p 4*B*HWP*32 = 4,326,400
    //   xg 2,097,152 | h1p 2*B*HWP*32 = 2,163,200 | h2p 2,163,200
    //   w1A 73,728 | w2A 36,864 | w3A 248,832 | wkA 36,864
    _Float16* omh  = (_Float16*)d_ws;
    _Float16* valh = omh + (size_t)B_ * OFFC_ * HW_;
    _Float16* ef_p = valh + (size_t)18 * B_ * HW_ * 32;
    _Float16* xg   = ef_p + (size_t)4 * B_ * HWP_ * 32;
    _Float16* h1p  = xg + (size_t)B_ * HW_ * 64;
    _Float16* h2p  = h1p + (size_t)2 * B_ * HWP_ * 32;
    _Float16* w1A  = h2p + (size_t)2 * B_ * HWP_ * 32;
    _Float16* w2A  = w1A + 64 * 128 * 9;
    _Float16* w3A  = w2A + 64 * 64 * 9;
    _Float16* wkA  = w3A + OFFC_ * 64 * 9;

    // Zero the padded buffers (borders must be 0; interiors overwritten).
    hipMemsetAsync(ef_p, 0, (size_t)4 * B_ * HWP_ * 32 * 2, stream);
    hipMemsetAsync(h1p, 0, (size_t)2 * B_ * HWP_ * 32 * 2, stream);
    hipMemsetAsync(h2p, 0, (size_t)2 * B_ * HWP_ * 32 * 2, stream);

    prep_wA_k<64, 128><<<dim3((64 * 128 * 9 + 255) / 256), 256, 0, stream>>>(w1, w1A);
    prep_wA_k<64, 64><<<dim3((64 * 64 * 9 + 255) / 256), 256, 0, stream>>>(w2, w2A);
    prep_wA_k<OFFC_, 64><<<dim3((OFFC_ * 64 * 9 + 255) / 256), 256, 0, stream>>>(w3, w3A);
    prep_wkA_k<<<dim3((18 * 64 * 32 + 255) / 256), 256, 0, stream>>>(wk, wkA);
    nchw2slabpad_f16_k<128><<<dim3(HW_ / 256, B_), 256, 0, stream>>>(ef, ef_p);
    nchw2gx_f16_k<<<dim3(HW_ / 256, B_), 256, 0, stream>>>(x, xg);

    conv1_mfma_k<<<dim3(B_ * H_ * 2), 256, 0, stream>>>(ef_p, w1A, b1, h1p);
    conv2_mfma_k<<<dim3(B_ * H_ * 2), 256, 0, stream>>>(h1p, w2A, b2, h2p);
    conv3_mfma_k<<<dim3(B_ * H_ * 2, 9), 256, 0, stream>>>(h2p, w3A, b3, flow, omh);

    gather_k<<<dim3(HW_ / 256, B_ * KK_), 256, 0, stream>>>(xg, omh, valh);
    einsum_mfma_k<<<dim3(B_ * HW_ / 64), 256, 0, stream>>>(valh, wkA, out);
}

// Round 9
// 209.418 us; speedup vs baseline: 1.0664x; 1.0664x over previous
//
#include <hip/hip_runtime.h>
#include <math.h>

// Problem constants (fixed by setup_inputs)
constexpr int B_   = 2;
constexpr int C_   = 64;
constexpr int H_   = 128;
constexpr int W_   = 128;
constexpr int HW_  = H_ * W_;
constexpr int DG_  = 16;   // deformable groups
constexpr int KK_  = 9;    // 3x3 taps
constexpr int CG_  = 4;    // channels per group = C/DG
constexpr int OFFC_ = 3 * KK_ * DG_;  // 432
constexpr int R_   = C_ * KK_;        // 576 reduction length
constexpr int WP_  = 130;             // padded width/height
constexpr int HWP_ = WP_ * WP_;       // 16900 padded pixels

typedef _Float16 half8 __attribute__((ext_vector_type(8)));  // 8 f16 = 4 VGPR
typedef _Float16 half4 __attribute__((ext_vector_type(4)));  // 8-byte load/store
typedef float floatx4 __attribute__((ext_vector_type(4)));   // MFMA acc

// Async global->LDS DMA, 16 B per lane. LDS dest is wave-uniform base +
// lane*16 (m104); every call site passes exactly that shape.
__device__ __forceinline__ void gl_lds16(const _Float16* g, _Float16* l)
{
    __builtin_amdgcn_global_load_lds(
        (const __attribute__((address_space(1))) void*)g,
        (__attribute__((address_space(3))) void*)l, 16, 0, 0);
}

// Fragment-major A staging: LDS chunk c (16 B) holds the data fragment
// (mf = c>>6) needs at lane (c&63): global f16 index within the K-slice.
// Reader then does afr[mf] = lds[base + lane*16 + mf*1024] -> addresses
// linear in lane -> conflict-free ds_read_b128.
__device__ __forceinline__ int afrag_src(int c)
{
    const int cmf = c >> 6, cq = (c >> 4) & 3, cl = c & 15;
    return (cmf * 16 + cl) * 32 + cq * 8;
}

// ---------------------------------------------------------------------------
// Generic MFMA A-operand prep: wA[(t*CH+h)*OC + oc][j] = f16(w[oc][(h*32+j)*9+t])
// ---------------------------------------------------------------------------
template <int OC, int CIN>
__global__ __launch_bounds__(256) void prep_wA_k(
    const float* __restrict__ w, _Float16* __restrict__ wA)
{
    constexpr int CH = CIN / 32;
    const int j = blockIdx.x * 256 + threadIdx.x;   // slab*OC*32 + oc*32 + jj
    if (j >= 9 * CH * OC * 32) return;
    const int slab = j / (OC * 32);
    const int rem  = j - slab * (OC * 32);
    const int oc   = rem >> 5;
    const int jj   = rem & 31;
    const int t    = slab / CH;
    const int h    = slab - t * CH;
    const int ic   = h * 32 + jj;
    wA[j] = (_Float16)w[(size_t)oc * (CIN * 9) + ic * 9 + t];
}

// ---------------------------------------------------------------------------
// Einsum A-operand prep: r = k*64 + gc (gc = g*4+c).  18 slabs of 32.
// ---------------------------------------------------------------------------
__global__ __launch_bounds__(256) void prep_wkA_k(
    const float* __restrict__ wk, _Float16* __restrict__ wkA)
{
    const int j = blockIdx.x * 256 + threadIdx.x;   // s*2048 + oc*32 + jj
    if (j >= 18 * 64 * 32) return;
    const int s   = j >> 11;
    const int rem = j & 2047;
    const int oc  = rem >> 5;
    const int jj  = rem & 31;
    const int k   = s >> 1;
    const int gc  = (s & 1) * 32 + jj;
    wkA[j] = (_Float16)wk[(size_t)oc * R_ + gc * 9 + k];
}

// ---------------------------------------------------------------------------
// NCHW fp32 -> PADDED slab-split f16: out[(c/32)*B + b][y+1][x+1][32].
// ---------------------------------------------------------------------------
template <int CC>
__global__ __launch_bounds__(256) void nchw2slabpad_f16_k(
    const float* __restrict__ in, _Float16* __restrict__ outh)
{
    const int pix = blockIdx.x * 256 + threadIdx.x;
    const int b   = blockIdx.y;
    const int yp  = pix >> 7;
    const int xp  = pix & (W_ - 1);
    const float* ib = in + (size_t)b * CC * HW_ + pix;
#pragma unroll
    for (int c0 = 0; c0 < CC; c0 += 8) {
        half8 v;
#pragma unroll
        for (int j = 0; j < 8; ++j)
            v[j] = (_Float16)ib[(size_t)(c0 + j) * HW_];
        const int slab = c0 >> 5;
        *(half8*)&outh[((size_t)(slab * B_ + b) * HWP_
                        + (size_t)(yp + 1) * WP_ + (xp + 1)) * 32 + (c0 & 31)] = v;
    }
}

// ---------------------------------------------------------------------------
// NCHW fp32 -> per-group planes f16: xg[((b*DG+g)*HW + pix)*4 + c].
// ---------------------------------------------------------------------------
__global__ __launch_bounds__(256) void nchw2gx_f16_k(
    const float* __restrict__ in, _Float16* __restrict__ outh)
{
    const int pix = blockIdx.x * 256 + threadIdx.x;
    const int b   = blockIdx.y;
    const float* ib = in + (size_t)b * C_ * HW_ + pix;
#pragma unroll
    for (int g = 0; g < DG_; ++g) {
        half4 v;
#pragma unroll
        for (int c = 0; c < 4; ++c)
            v[c] = (_Float16)ib[(size_t)(g * 4 + c) * HW_];
        *(half4*)&outh[((size_t)(b * DG_ + g) * HW_ + pix) * 4] = v;
    }
}

// ---------------------------------------------------------------------------
// Conv1 (128 -> 64) via f16 MFMA. Wave tile = 64 oc x 16 px (mf=4).
// 2 K-steps per barrier phase (36 steps -> 18 phases). A dbuf = 16 KB.
// ---------------------------------------------------------------------------
__global__ __launch_bounds__(256, 2) void conv1_mfma_k(
    const _Float16* __restrict__ inp, const _Float16* __restrict__ wA,
    const float* __restrict__ bias, _Float16* __restrict__ outp)
{
    __shared__ __align__(16) _Float16 Asm[2 * 4096];   // 16 KB

    const int tid  = threadIdx.x;
    const int lane = tid & 63;
    const int wv   = tid >> 6;
    const int l15  = lane & 15;
    const int quad = lane >> 4;

    const int zx   = blockIdx.x;          // (b*H + y)*2 + half64
    const int row  = zx >> 1;
    const int b    = row >> 7;
    const int y    = row & 127;
    const int px0  = (zx & 1) * 64 + wv * 16;

    const int sA = afrag_src(tid);        // global f16 offset for my chunk

    floatx4 acc[4];
#pragma unroll
    for (int mf = 0; mf < 4; ++mf)
        acc[mf] = (floatx4){0.f, 0.f, 0.f, 0.f};

    half8 Bf[2][2];                       // [phase buf][slice]

    // prologue: stage phase 0 (ks=0,1 -> t=0, h=0,1), load B ks=0,1
    gl_lds16(wA + 0 * 2048 + sA, Asm + 0 * 2048 + tid * 8);
    gl_lds16(wA + 1 * 2048 + sA, Asm + 1 * 2048 + tid * 8);
#pragma unroll
    for (int j = 0; j < 2; ++j)
        Bf[0][j] = *(const half8*)&inp[
            ((size_t)(j * B_ + b) * HWP_ + (size_t)(y + 0) * WP_
             + (px0 + l15 + 0)) * 32 + quad * 8];
    __syncthreads();

#pragma unroll
    for (int p = 0; p < 18; ++p) {        // phase p covers ks = 2p, 2p+1
        const int cur = p & 1, nxt = cur ^ 1;
        if (p < 17) {
            const int ks0 = 2 * p + 2;    // first slice of next phase
            const int t = ks0 >> 2;       // CH=4: ks = t*4 + h
            const int h0 = ks0 & 3;       // and h0+1 for the second slice
            const int dy = t / 3, dx = t % 3;
#pragma unroll
            for (int j = 0; j < 2; ++j) {
                gl_lds16(wA + (size_t)(ks0 + j) * 2048 + sA,
                         Asm + (nxt * 2 + j) * 2048 + tid * 8);
                Bf[nxt][j] = *(const half8*)&inp[
                    ((size_t)((h0 + j) * B_ + b) * HWP_ + (size_t)(y + dy) * WP_
                     + (px0 + l15 + dx)) * 32 + quad * 8];
            }
        }
#pragma unroll
        for (int j = 0; j < 2; ++j) {
            const _Float16* abase = Asm + (cur * 2 + j) * 2048 + lane * 8;
#pragma unroll
            for (int mf = 0; mf < 4; ++mf) {
                const half8 afr = *(const half8*)&abase[mf * 512];
                acc[mf] = __builtin_amdgcn_mfma_f32_16x16x32_f16(afr, Bf[cur][j], acc[mf], 0, 0, 0);
            }
        }
        __syncthreads();   // drains vmcnt: next phase's A/B landed
    }

    // epilogue: leaky ReLU, padded slab-split f16 store (8 B/lane x 4 tiles)
#pragma unroll
    for (int mf = 0; mf < 4; ++mf) {
        const int oc4 = mf * 16 + quad * 4;        // first of 4 output chans
        const float4 b4 = *(const float4*)&bias[oc4];
        half4 v4;
#pragma unroll
        for (int reg = 0; reg < 4; ++reg) {
            float r = acc[mf][reg] + ((const float*)&b4)[reg];
            r = (r >= 0.f) ? r : 0.1f * r;
            v4[reg] = (_Float16)r;
        }
        *(half4*)&outp[((size_t)((oc4 >> 5) * B_ + b) * HWP_
                        + (size_t)(y + 1) * WP_ + (px0 + l15 + 1)) * 32 + (oc4 & 31)] = v4;
    }
}

// ---------------------------------------------------------------------------
// Conv2 (64 -> 64) via f16 MFMA. Wave tile = 64 oc x 16 px (mf=4).
// FULL A preload (72 KB LDS), barrier-free 18-step K-loop.
// v8: per-step B addressing is ZERO-VALU -- six {h,dy} base pointers
// precomputed once; in-loop loads use compile-time byte immediates only.
// ---------------------------------------------------------------------------
__global__ __launch_bounds__(256, 2) void conv2_mfma_k(
    const _Float16* __restrict__ inp, const _Float16* __restrict__ wA,
    const float* __restrict__ bias, _Float16* __restrict__ outp)
{
    __shared__ __align__(16) _Float16 Asm[18 * 2048];   // 73728 B

    const int tid  = threadIdx.x;
    const int lane = tid & 63;
    const int wv   = tid >> 6;
    const int l15  = lane & 15;
    const int quad = lane >> 4;

    const int zx   = blockIdx.x;          // (b*H + y)*2 + half64
    const int row  = zx >> 1;
    const int b    = row >> 7;
    const int y    = row & 127;
    const int px0  = (zx & 1) * 64 + wv * 16;

    const int sA = afrag_src(tid);

    // full preload: 18 slabs x 4 KB
#pragma unroll
    for (int s = 0; s < 18; ++s)
        gl_lds16(wA + (size_t)s * 2048 + sA, Asm + s * 2048 + tid * 8);

    // six {h, dy} B base pointers (all per-step variation is an immediate)
    const _Float16* bb[6];
#pragma unroll
    for (int h = 0; h < 2; ++h)
#pragma unroll
        for (int dy = 0; dy < 3; ++dy)
            bb[h * 3 + dy] = inp + ((size_t)(h * B_ + b) * HWP_
                                    + (size_t)(y + dy) * WP_ + px0 + l15) * 32 + quad * 8;

    floatx4 acc[4];
#pragma unroll
    for (int mf = 0; mf < 4; ++mf)
        acc[mf] = (floatx4){0.f, 0.f, 0.f, 0.f};

    __syncthreads();   // preload (all waves) visible

    const _Float16* abase = Asm + lane * 8;
#pragma unroll
    for (int ks = 0; ks < 18; ++ks) {     // ks = t*2 + h  (CH=2)
        const int t = ks >> 1, h = ks & 1;
        const int dy = t / 3, dx = t % 3;
        const half8 bfr = *(const half8*)&bb[h * 3 + dy][dx * 32];
#pragma unroll
        for (int mf = 0; mf < 4; ++mf) {
            const half8 afr = *(const half8*)&abase[ks * 2048 + mf * 512];
            acc[mf] = __builtin_amdgcn_mfma_f32_16x16x32_f16(afr, bfr, acc[mf], 0, 0, 0);
        }
    }

    // epilogue: leaky ReLU, padded slab-split f16 store
#pragma unroll
    for (int mf = 0; mf < 4; ++mf) {
        const int oc4 = mf * 16 + quad * 4;
        const float4 b4 = *(const float4*)&bias[oc4];
        half4 v4;
#pragma unroll
        for (int reg = 0; reg < 4; ++reg) {
            float r = acc[mf][reg] + ((const float*)&b4)[reg];
            r = (r >= 0.f) ? r : 0.1f * r;
            v4[reg] = (_Float16)r;
        }
        *(half4*)&outp[((size_t)((oc4 >> 5) * B_ + b) * HWP_
                        + (size_t)(y + 1) * WP_ + (px0 + l15 + 1)) * 32 + (oc4 & 31)] = v4;
    }
}

// ---------------------------------------------------------------------------
// Conv3 via f16 MFMA implicit GEMM.
// v8 = v6 structure (48-oc tile, A slices 0..16 in LDS @ 3 blocks/CU,
// slice 17 in regs, barrier-free K-loop, B from global/L1) with ZERO-VALU
// in-loop addressing: six {h,dy} B base pointers precomputed, per-step
// offsets are compile-time immediates; loop split at the LDS/reg A boundary
// so no in-loop selects. v6's counters showed VALU (35%) was the largest
// pipe -- 64-bit B-address recomputation per step -- not memory latency.
// ---------------------------------------------------------------------------
__global__ __launch_bounds__(256, 3) void conv3_mfma_k(
    const _Float16* __restrict__ h2p, const _Float16* __restrict__ w3A,
    const float* __restrict__ bias, const float* __restrict__ flow,
    _Float16* __restrict__ omh)
{
    __shared__ __align__(16) _Float16 Smem[17 * 1536];   // 52224 B (union)
    _Float16* Lds = Smem;                                // epilogue view

    const int tid  = threadIdx.x;
    const int lane = tid & 63;
    const int wv   = tid >> 6;       // wave id 0..3
    const int l15  = lane & 15;
    const int quad = lane >> 4;

    const int row = blockIdx.x;      // b*128 + y
    const int b   = row >> 7;
    const int y   = row & 127;
    const int m0  = blockIdx.y * 48; // oc tile base (0..384)
    const int px0 = wv * 32;

    // ---- full-K A preload, slices 0..16, fragment-major ----
#pragma unroll
    for (int r = 0; r < 13; ++r) {
        const int c = r * 256 + tid;          // global chunk id
        if (c < 17 * 192) {
            const int ks = c / 192;
            const int cl = c - ks * 192;      // chunk within slice
            const int cmf = cl >> 6, cq = (cl >> 4) & 3, ccl = cl & 15;
            gl_lds16(w3A + ((size_t)ks * OFFC_ + m0 + cmf * 16 + ccl) * 32 + cq * 8,
                     Smem + c * 8);
        }
    }

    // slice 17's A-fragments direct to registers (drained by the barrier)
    half8 Af17[3];
#pragma unroll
    for (int mf = 0; mf < 3; ++mf)
        Af17[mf] = *(const half8*)&w3A[
            ((size_t)17 * OFFC_ + m0 + mf * 16 + l15) * 32 + quad * 8];

    // six {h, dy} B base pointers; per-step variation = immediate offsets
    const _Float16* bb[6];
#pragma unroll
    for (int h = 0; h < 2; ++h)
#pragma unroll
        for (int dy = 0; dy < 3; ++dy)
            bb[h * 3 + dy] = h2p + ((size_t)(h * B_ + b) * HWP_
                                    + (size_t)(y + dy) * WP_ + px0 + l15) * 32 + quad * 8;

    floatx4 acc[3][2];
#pragma unroll
    for (int mf = 0; mf < 3; ++mf)
#pragma unroll
        for (int nf = 0; nf < 2; ++nf)
            acc[mf][nf] = (floatx4){0.f, 0.f, 0.f, 0.f};

    __syncthreads();   // preload visible (single drain before the loop)

    // ---- barrier-free K-loop, zero in-loop VALU address math ----
    const _Float16* abase = Smem + lane * 8;
#pragma unroll
    for (int ks = 0; ks < 17; ++ks) {           // ks = t*2 + h, A from LDS
        const int t = ks >> 1, h = ks & 1;
        const int dy = t / 3, dx = t % 3;
        const half8 b0 = *(const half8*)&bb[h * 3 + dy][dx * 32];
        const half8 b1 = *(const half8*)&bb[h * 3 + dy][(16 + dx) * 32];
#pragma unroll
        for (int mf = 0; mf < 3; ++mf) {
            const half8 afr = *(const half8*)&abase[ks * 1536 + mf * 512];
            acc[mf][0] = __builtin_amdgcn_mfma_f32_16x16x32_f16(afr, b0, acc[mf][0], 0, 0, 0);
            acc[mf][1] = __builtin_amdgcn_mfma_f32_16x16x32_f16(afr, b1, acc[mf][1], 0, 0, 0);
        }
    }
    {   // ks = 17: t=8 (dy=2, dx=2), h=1; A from registers
        const half8 b0 = *(const half8*)&bb[5][2 * 32];
        const half8 b1 = *(const half8*)&bb[5][(16 + 2) * 32];
#pragma unroll
        for (int mf = 0; mf < 3; ++mf) {
            acc[mf][0] = __builtin_amdgcn_mfma_f32_16x16x32_f16(Af17[mf], b0, acc[mf][0], 0, 0, 0);
            acc[mf][1] = __builtin_amdgcn_mfma_f32_16x16x32_f16(Af17[mf], b1, acc[mf][1], 0, 0, 0);
        }
    }
    __syncthreads();   // all waves done reading Smem; safe to alias Lds

    // ---- transform + stage to LDS (f16, 48 rows x 128 px, pad to 132) ----
    const bool is_off = (blockIdx.y < 6);     // block-uniform: m0 < 288
    float flY[2], flX[2];
#pragma unroll
    for (int nf = 0; nf < 2; ++nf) {
        const int px = px0 + nf * 16 + l15;
        if (is_off) {
            flY[nf] = flow[(size_t)(b * 2 + 1) * HW_ + y * W_ + px]; // slot 0 (y)
            flX[nf] = flow[(size_t)(b * 2 + 0) * HW_ + y * W_ + px]; // slot 1 (x)
        }
    }
#pragma unroll
    for (int mf = 0; mf < 3; ++mf) {
        const float4 b4 = *(const float4*)&bias[m0 + mf * 16 + quad * 4];
#pragma unroll
        for (int nf = 0; nf < 2; ++nf) {
            const int px = px0 + nf * 16 + l15;
#pragma unroll
            for (int reg = 0; reg < 4; ++reg) {
                const int ocl = mf * 16 + quad * 4 + reg;   // 0..47
                float val = acc[mf][nf][reg] + ((const float*)&b4)[reg];
                if (is_off) {                       // offset channels
                    const int slot = reg & 1;       // 0 = y, 1 = x
                    const float fl = slot ? flX[nf] : flY[nf];
                    const float e = __expf(2.f * val);      // tanh via exp
                    val = 10.f * (1.f - __fdividef(2.f, e + 1.f)) + fl;
                } else {                            // mask channels: sigmoid
                    val = __fdividef(1.f, 1.f + __expf(-val));
                }
                Lds[ocl * 132 + px] = (_Float16)val;
            }
        }
    }
    __syncthreads();   // LDS read-only hereafter

    // ---- contiguous f16 copy-out: 48 plane-rows x 128 px ----
#pragma unroll
    for (int it = 0; it < 6; ++it) {
        const int j4 = it * 256 + tid;
        const int r  = j4 >> 5;          // 0..47
        const int c4 = j4 & 31;          // half4 col
        const int oc = m0 + r;
        int g, k, slot;
        if (oc < 2 * DG_ * KK_) {
            g = oc / 18;
            const int rem = oc - g * 18;
            k = rem >> 1;
            slot = rem & 1;
        } else {
            const int c = oc - 2 * DG_ * KK_;
            g = c / 9;
            k = c - g * 9;
            slot = 2;
        }
        const half4 hv = *(const half4*)&Lds[r * 132 + c4 * 4];
        *(half4*)&omh[((size_t)((b * DG_ * KK_ + g * KK_ + k) * 3 + slot)) * HW_
                      + y * W_ + c4 * 4] = hv;
    }
}

// ---------------------------------------------------------------------------
// Phase A: bilinear gather, PIXEL-MAJOR lanes. Thread = one pixel for a
// fixed (b,k); loops g=0..15 in registers.
// ---------------------------------------------------------------------------
__global__ __launch_bounds__(256) void gather_k(
    const _Float16* __restrict__ xg, const _Float16* __restrict__ omh,
    _Float16* __restrict__ valh)
{
    const int tid = threadIdx.x;
    const int pix = blockIdx.x * 256 + tid;
    const int zy  = blockIdx.y;               // b*9 + k
    const int b   = zy / KK_;
    const int k   = zy - b * KK_;
    const int yp  = pix >> 7;
    const int xp  = pix & (W_ - 1);
    const float fy = (float)(yp + (k / 3) - 1);
    const float fx = (float)(xp + (k % 3) - 1);

    half4 rec[16];
#pragma unroll
    for (int g = 0; g < DG_; ++g) {
        const size_t obase = ((size_t)((b * DG_ + g) * KK_ + k) * 3) * HW_ + pix;
        const float oy = (float)omh[obase];
        const float ox = (float)omh[obase + HW_];
        const float m  = (float)omh[obase + 2 * HW_];

        const float py = fy + oy;
        const float px = fx + ox;
        const float y0f = floorf(py);
        const float x0f = floorf(px);
        const float wy = py - y0f;
        const float wx = px - x0f;
        const int y0 = (int)y0f, x0 = (int)x0f;
        const int y1 = y0 + 1,  x1 = x0 + 1;
        const bool vy0 = ((unsigned)y0 < (unsigned)H_);
        const bool vy1 = ((unsigned)y1 < (unsigned)H_);
        const bool vx0 = ((unsigned)x0 < (unsigned)W_);
        const bool vx1 = ((unsigned)x1 < (unsigned)W_);
        const float w00 = vy0 && vx0 ? (1.f - wy) * (1.f - wx) : 0.f;
        const float w01 = vy0 && vx1 ? (1.f - wy) * wx         : 0.f;
        const float w10 = vy1 && vx0 ? wy * (1.f - wx)         : 0.f;
        const float w11 = vy1 && vx1 ? wy * wx                 : 0.f;
        const int i00 = (vy0 && vx0) ? y0 * W_ + x0 : 0;
        const int i01 = (vy0 && vx1) ? y0 * W_ + x1 : 0;
        const int i10 = (vy1 && vx0) ? y1 * W_ + x0 : 0;
        const int i11 = (vy1 && vx1) ? y1 * W_ + x1 : 0;

        const _Float16* xb = xg + (size_t)(b * DG_ + g) * HW_ * 4;
        const half4 p00 = *(const half4*)&xb[(size_t)i00 * 4];
        const half4 p01 = *(const half4*)&xb[(size_t)i01 * 4];
        const half4 p10 = *(const half4*)&xb[(size_t)i10 * 4];
        const half4 p11 = *(const half4*)&xb[(size_t)i11 * 4];

        half4 v4;
#pragma unroll
        for (int c = 0; c < CG_; ++c) {
            float v = w00 * (float)p00[c] + w01 * (float)p01[c]
                    + w10 * (float)p10[c] + w11 * (float)p11[c];
            v4[c] = (_Float16)(v * m);
        }
        rec[g] = v4;
    }

    // write slabs s = 2k (g 0..7) and 2k+1 (g 8..15): 64 B each, contiguous
    _Float16* r0 = &valh[((size_t)((2 * k) * B_ + b) * HW_ + pix) * 32];
    _Float16* r1 = &valh[((size_t)((2 * k + 1) * B_ + b) * HW_ + pix) * 32];
#pragma unroll
    for (int j = 0; j < 4; ++j) {
        half8 w0, w1;
#pragma unroll
        for (int c = 0; c < 4; ++c) {
            w0[c]     = rec[2 * j][c];
            w0[c + 4] = rec[2 * j + 1][c];
            w1[c]     = rec[8 + 2 * j][c];
            w1[c + 4] = rec[9 + 2 * j][c];
        }
        *(half8*)&r0[j * 8] = w0;
        *(half8*)&r1[j * 8] = w1;
    }
}

// ---------------------------------------------------------------------------
// Phase B: einsum via f16 MFMA. Wave = 16 px x 64 oc (mf=4).
// FULL A preload (72 KB), barrier-free 18-step loop, epilogue aliases A.
// ---------------------------------------------------------------------------
__global__ __launch_bounds__(256, 2) void einsum_mfma_k(
    const _Float16* __restrict__ valh, const _Float16* __restrict__ wkA,
    float* __restrict__ out)
{
    __shared__ __align__(16) _Float16 Smem[18 * 2048];  // 73728 B (union)
    float* Lds = (float*)Smem;                          // epilogue view

    const int tid  = threadIdx.x;
    const int lane = tid & 63;
    const int wv   = tid >> 6;
    const int l15  = lane & 15;
    const int quad = lane >> 4;

    const int pixg0 = blockIdx.x * 64 + wv * 16;    // global pixel (b*HW+pix)
    const int b     = pixg0 >> 14;
    const int pix0  = pixg0 & (HW_ - 1);

    const int sA = afrag_src(tid);

    // full preload: 18 slabs x 4 KB
#pragma unroll
    for (int s = 0; s < 18; ++s)
        gl_lds16(wkA + (size_t)s * 2048 + sA, Smem + s * 2048 + tid * 8);

    floatx4 acc[4];
#pragma unroll
    for (int mf = 0; mf < 4; ++mf)
        acc[mf] = (floatx4){0.f, 0.f, 0.f, 0.f};

    half8 Bf[2];
    Bf[0] = *(const half8*)&valh[((size_t)(0 * B_ + b) * HW_ + pix0 + l15) * 32 + quad * 8];
    __syncthreads();   // preload visible

#pragma unroll
    for (int s = 0; s < 18; ++s) {
        const int cur = s & 1, nxt = cur ^ 1;
        if (s < 17) {
            const int s1 = s + 1;
            Bf[nxt] = *(const half8*)&valh[
                ((size_t)(s1 * B_ + b) * HW_ + pix0 + l15) * 32 + quad * 8];
        }
        const _Float16* abase = Smem + s * 2048 + lane * 8;
#pragma unroll
        for (int mf = 0; mf < 4; ++mf) {
            const half8 afr = *(const half8*)&abase[mf * 512];
            acc[mf] = __builtin_amdgcn_mfma_f32_16x16x32_f16(afr, Bf[cur], acc[mf], 0, 0, 0);
        }
    }
    __syncthreads();   // all waves done reading A; safe to alias

    // ---- stage 64 oc x 64 px tile to LDS ----
    const int pxl = wv * 16 + l15;                  // 0..63 block-local pixel
#pragma unroll
    for (int mf = 0; mf < 4; ++mf)
#pragma unroll
        for (int reg = 0; reg < 4; ++reg)
            Lds[(mf * 16 + quad * 4 + reg) * 68 + pxl] = acc[mf][reg];
    __syncthreads();   // LDS read-only hereafter

    // ---- coalesced copy-out: 64 oc-rows x 64 px (16 float4 per row) ----
    const int pixb = blockIdx.x * 64 & (HW_ - 1);   // block-base pixel
#pragma unroll
    for (int it = 0; it < 4; ++it) {
        const int j4 = it * 256 + tid;
        const int r  = j4 >> 4;                     // oc 0..63
        const int c4 = j4 & 15;                     // float4 col
        float4 v;
        v.x = Lds[r * 68 + c4 * 4 + 0];
        v.y = Lds[r * 68 + c4 * 4 + 1];
        v.z = Lds[r * 68 + c4 * 4 + 2];
        v.w = Lds[r * 68 + c4 * 4 + 3];
        *(float4*)&out[((size_t)(b * C_ + r)) * HW_ + pixb + c4 * 4] = v;
    }
}

// ---------------------------------------------------------------------------
extern "C" void kernel_launch(void* const* d_in, const int* in_sizes, int n_in,
                              void* d_out, int out_size, void* d_ws, size_t ws_size,
                              hipStream_t stream)
{
    const float* x    = (const float*)d_in[0];
    const float* ef   = (const float*)d_in[1];
    const float* flow = (const float*)d_in[2];
    const float* w1   = (const float*)d_in[3];
    const float* b1   = (const float*)d_in[4];
    const float* w2   = (const float*)d_in[5];
    const float* b2   = (const float*)d_in[6];
    const float* w3   = (const float*)d_in[7];
    const float* b3   = (const float*)d_in[8];
    const float* wk   = (const float*)d_in[9];
    float* out = (float*)d_out;

    // Workspace (half slots):
    //   omh 14,155,776 | valh 18,874,368 | ef_p 4*B*HWP*32 = 4,326,400
    //   xg 2,097,152 | h1p 2*B*HWP*32 = 2,163,200 | h2p 2,163,200
    //   w1A 73,728 | w2A 36,864 | w3A 248,832 | wkA 36,864
    _Float16* omh  = (_Float16*)d_ws;
    _Float16* valh = omh + (size_t)B_ * OFFC_ * HW_;
    _Float16* ef_p = valh + (size_t)18 * B_ * HW_ * 32;
    _Float16* xg   = ef_p + (size_t)4 * B_ * HWP_ * 32;
    _Float16* h1p  = xg + (size_t)B_ * HW_ * 64;
    _Float16* h2p  = h1p + (size_t)2 * B_ * HWP_ * 32;
    _Float16* w1A  = h2p + (size_t)2 * B_ * HWP_ * 32;
    _Float16* w2A  = w1A + 64 * 128 * 9;
    _Float16* w3A  = w2A + 64 * 64 * 9;
    _Float16* wkA  = w3A + OFFC_ * 64 * 9;

    // Zero the padded buffers (borders must be 0; interiors overwritten).
    hipMemsetAsync(ef_p, 0, (size_t)4 * B_ * HWP_ * 32 * 2, stream);
    hipMemsetAsync(h1p, 0, (size_t)2 * B_ * HWP_ * 32 * 2, stream);
    hipMemsetAsync(h2p, 0, (size_t)2 * B_ * HWP_ * 32 * 2, stream);

    prep_wA_k<64, 128><<<dim3((64 * 128 * 9 + 255) / 256), 256, 0, stream>>>(w1, w1A);
    prep_wA_k<64, 64><<<dim3((64 * 64 * 9 + 255) / 256), 256, 0, stream>>>(w2, w2A);
    prep_wA_k<OFFC_, 64><<<dim3((OFFC_ * 64 * 9 + 255) / 256), 256, 0, stream>>>(w3, w3A);
    prep_wkA_k<<<dim3((18 * 64 * 32 + 255) / 256), 256, 0, stream>>>(wk, wkA);
    nchw2slabpad_f16_k<128><<<dim3(HW_ / 256, B_), 256, 0, stream>>>(ef, ef_p);
    nchw2gx_f16_k<<<dim3(HW_ / 256, B_), 256, 0, stream>>>(x, xg);

    conv1_mfma_k<<<dim3(B_ * H_ * 2), 256, 0, stream>>>(ef_p, w1A, b1, h1p);
    conv2_mfma_k<<<dim3(B_ * H_ * 2), 256, 0, stream>>>(h1p, w2A, b2, h2p);
    conv3_mfma_k<<<dim3(B_ * H_, 9), 256, 0, stream>>>(h2p, w3A, b3, flow, omh);

    gather_k<<<dim3(HW_ / 256, B_ * KK_), 256, 0, stream>>>(xg, omh, valh);
    einsum_mfma_k<<<dim3(B_ * HW_ / 64), 256, 0, stream>>>(valh, wkA, out);
}

// Round 10
// 206.256 us; speedup vs baseline: 1.0827x; 1.0153x over previous
//
#include <hip/hip_runtime.h>
#include <math.h>

// Problem constants (fixed by setup_inputs)
constexpr int B_   = 2;
constexpr int C_   = 64;
constexpr int H_   = 128;
constexpr int W_   = 128;
constexpr int HW_  = H_ * W_;
constexpr int DG_  = 16;   // deformable groups
constexpr int KK_  = 9;    // 3x3 taps
constexpr int CG_  = 4;    // channels per group = C/DG
constexpr int OFFC_ = 3 * KK_ * DG_;  // 432
constexpr int R_   = C_ * KK_;        // 576 reduction length
constexpr int WP_  = 130;             // padded width/height
constexpr int HWP_ = WP_ * WP_;       // 16900 padded pixels

typedef _Float16 half8 __attribute__((ext_vector_type(8)));  // 8 f16 = 4 VGPR
typedef _Float16 half4 __attribute__((ext_vector_type(4)));  // 8-byte load/store
typedef float floatx4 __attribute__((ext_vector_type(4)));   // MFMA acc

// Async global->LDS DMA, 16 B per lane. LDS dest is wave-uniform base +
// lane*16 (m104); every call site passes exactly that shape.
__device__ __forceinline__ void gl_lds16(const _Float16* g, _Float16* l)
{
    __builtin_amdgcn_global_load_lds(
        (const __attribute__((address_space(1))) void*)g,
        (__attribute__((address_space(3))) void*)l, 16, 0, 0);
}

// Fragment-major A staging: LDS chunk c (16 B) holds the data fragment
// (mf = c>>6) needs at lane (c&63): global f16 index within the K-slice.
// Reader then does afr[mf] = lds[base + lane*16 + mf*1024] -> addresses
// linear in lane -> conflict-free ds_read_b128.
__device__ __forceinline__ int afrag_src(int c)
{
    const int cmf = c >> 6, cq = (c >> 4) & 3, cl = c & 15;
    return (cmf * 16 + cl) * 32 + cq * 8;
}

// ---------------------------------------------------------------------------
// Generic MFMA A-operand prep: wA[(t*CH+h)*OC + oc][j] = f16(w[oc][(h*32+j)*9+t])
// ---------------------------------------------------------------------------
template <int OC, int CIN>
__global__ __launch_bounds__(256) void prep_wA_k(
    const float* __restrict__ w, _Float16* __restrict__ wA)
{
    constexpr int CH = CIN / 32;
    const int j = blockIdx.x * 256 + threadIdx.x;   // slab*OC*32 + oc*32 + jj
    if (j >= 9 * CH * OC * 32) return;
    const int slab = j / (OC * 32);
    const int rem  = j - slab * (OC * 32);
    const int oc   = rem >> 5;
    const int jj   = rem & 31;
    const int t    = slab / CH;
    const int h    = slab - t * CH;
    const int ic   = h * 32 + jj;
    wA[j] = (_Float16)w[(size_t)oc * (CIN * 9) + ic * 9 + t];
}

// ---------------------------------------------------------------------------
// Einsum A-operand prep: r = k*64 + gc (gc = g*4+c).  18 slabs of 32.
// ---------------------------------------------------------------------------
__global__ __launch_bounds__(256) void prep_wkA_k(
    const float* __restrict__ wk, _Float16* __restrict__ wkA)
{
    const int j = blockIdx.x * 256 + threadIdx.x;   // s*2048 + oc*32 + jj
    if (j >= 18 * 64 * 32) return;
    const int s   = j >> 11;
    const int rem = j & 2047;
    const int oc  = rem >> 5;
    const int jj  = rem & 31;
    const int k   = s >> 1;
    const int gc  = (s & 1) * 32 + jj;
    wkA[j] = (_Float16)wk[(size_t)oc * R_ + gc * 9 + k];
}

// ---------------------------------------------------------------------------
// NCHW fp32 -> PADDED slab-split f16: out[(c/32)*B + b][y+1][x+1][32].
// ---------------------------------------------------------------------------
template <int CC>
__global__ __launch_bounds__(256) void nchw2slabpad_f16_k(
    const float* __restrict__ in, _Float16* __restrict__ outh)
{
    const int pix = blockIdx.x * 256 + threadIdx.x;
    const int b   = blockIdx.y;
    const int yp  = pix >> 7;
    const int xp  = pix & (W_ - 1);
    const float* ib = in + (size_t)b * CC * HW_ + pix;
#pragma unroll
    for (int c0 = 0; c0 < CC; c0 += 8) {
        half8 v;
#pragma unroll
        for (int j = 0; j < 8; ++j)
            v[j] = (_Float16)ib[(size_t)(c0 + j) * HW_];
        const int slab = c0 >> 5;
        *(half8*)&outh[((size_t)(slab * B_ + b) * HWP_
                        + (size_t)(yp + 1) * WP_ + (xp + 1)) * 32 + (c0 & 31)] = v;
    }
}

// ---------------------------------------------------------------------------
// NCHW fp32 -> per-group planes f16: xg[((b*DG+g)*HW + pix)*4 + c].
// ---------------------------------------------------------------------------
__global__ __launch_bounds__(256) void nchw2gx_f16_k(
    const float* __restrict__ in, _Float16* __restrict__ outh)
{
    const int pix = blockIdx.x * 256 + threadIdx.x;
    const int b   = blockIdx.y;
    const float* ib = in + (size_t)b * C_ * HW_ + pix;
#pragma unroll
    for (int g = 0; g < DG_; ++g) {
        half4 v;
#pragma unroll
        for (int c = 0; c < 4; ++c)
            v[c] = (_Float16)ib[(size_t)(g * 4 + c) * HW_];
        *(half4*)&outh[((size_t)(b * DG_ + g) * HW_ + pix) * 4] = v;
    }
}

// ---------------------------------------------------------------------------
// Conv1 (128 -> 64) via f16 MFMA. Wave tile = 64 oc x 16 px (mf=4).
// v9: split-K two-phase FULL preload (conv2's proven pattern x2): stage
// slabs 0..17 (72 KB) -> barrier -> 18 barrier-free K-steps -> barrier ->
// re-stage slabs 18..35 -> barrier -> 18 more steps. 3 barriers instead of
// 18 per-phase vmcnt(0) drains. In-loop addressing is zero-VALU: twelve
// {h,dy} B base pointers, per-step offsets are compile-time immediates.
// ---------------------------------------------------------------------------
__global__ __launch_bounds__(256, 2) void conv1_mfma_k(
    const _Float16* __restrict__ inp, const _Float16* __restrict__ wA,
    const float* __restrict__ bias, _Float16* __restrict__ outp)
{
    __shared__ __align__(16) _Float16 Asm[18 * 2048];   // 73728 B

    const int tid  = threadIdx.x;
    const int lane = tid & 63;
    const int wv   = tid >> 6;
    const int l15  = lane & 15;
    const int quad = lane >> 4;

    const int zx   = blockIdx.x;          // (b*H + y)*2 + half64
    const int row  = zx >> 1;
    const int b    = row >> 7;
    const int y    = row & 127;
    const int px0  = (zx & 1) * 64 + wv * 16;

    const int sA = afrag_src(tid);        // global f16 offset for my chunk

    // twelve {h 0..3, dy 0..2} B base pointers; per-step delta = immediate
    const _Float16* bb[12];
#pragma unroll
    for (int h = 0; h < 4; ++h)
#pragma unroll
        for (int dy = 0; dy < 3; ++dy)
            bb[h * 3 + dy] = inp + ((size_t)(h * B_ + b) * HWP_
                                    + (size_t)(y + dy) * WP_ + px0 + l15) * 32 + quad * 8;

    floatx4 acc[4];
#pragma unroll
    for (int mf = 0; mf < 4; ++mf)
        acc[mf] = (floatx4){0.f, 0.f, 0.f, 0.f};

    // ---- phase 0: preload slabs 0..17 ----
#pragma unroll
    for (int s = 0; s < 18; ++s)
        gl_lds16(wA + (size_t)s * 2048 + sA, Asm + s * 2048 + tid * 8);
    __syncthreads();   // staged + visible

    const _Float16* abase = Asm + lane * 8;
#pragma unroll
    for (int ks = 0; ks < 18; ++ks) {     // ks = t*4 + h  (CH=4)
        const int t = ks >> 2, h = ks & 3;
        const int dy = t / 3, dx = t % 3;
        const half8 bfr = *(const half8*)&bb[h * 3 + dy][dx * 32];
#pragma unroll
        for (int mf = 0; mf < 4; ++mf) {
            const half8 afr = *(const half8*)&abase[ks * 2048 + mf * 512];
            acc[mf] = __builtin_amdgcn_mfma_f32_16x16x32_f16(afr, bfr, acc[mf], 0, 0, 0);
        }
    }
    __syncthreads();   // all waves done reading phase-0 A

    // ---- phase 1: re-stage slabs 18..35 into the same LDS ----
#pragma unroll
    for (int s = 0; s < 18; ++s)
        gl_lds16(wA + (size_t)(18 + s) * 2048 + sA, Asm + s * 2048 + tid * 8);
    __syncthreads();   // staged + visible

#pragma unroll
    for (int ks = 18; ks < 36; ++ks) {
        const int t = ks >> 2, h = ks & 3;
        const int dy = t / 3, dx = t % 3;
        const half8 bfr = *(const half8*)&bb[h * 3 + dy][dx * 32];
#pragma unroll
        for (int mf = 0; mf < 4; ++mf) {
            const half8 afr = *(const half8*)&abase[(ks - 18) * 2048 + mf * 512];
            acc[mf] = __builtin_amdgcn_mfma_f32_16x16x32_f16(afr, bfr, acc[mf], 0, 0, 0);
        }
    }

    // epilogue: leaky ReLU, padded slab-split f16 store (8 B/lane x 4 tiles)
#pragma unroll
    for (int mf = 0; mf < 4; ++mf) {
        const int oc4 = mf * 16 + quad * 4;        // first of 4 output chans
        const float4 b4 = *(const float4*)&bias[oc4];
        half4 v4;
#pragma unroll
        for (int reg = 0; reg < 4; ++reg) {
            float r = acc[mf][reg] + ((const float*)&b4)[reg];
            r = (r >= 0.f) ? r : 0.1f * r;
            v4[reg] = (_Float16)r;
        }
        *(half4*)&outp[((size_t)((oc4 >> 5) * B_ + b) * HWP_
                        + (size_t)(y + 1) * WP_ + (px0 + l15 + 1)) * 32 + (oc4 & 31)] = v4;
    }
}

// ---------------------------------------------------------------------------
// Conv2 (64 -> 64) via f16 MFMA. Wave tile = 64 oc x 16 px (mf=4).
// FULL A preload (72 KB LDS), barrier-free 18-step K-loop, zero-VALU
// in-loop addressing (six {h,dy} base pointers, immediate offsets).
// ---------------------------------------------------------------------------
__global__ __launch_bounds__(256, 2) void conv2_mfma_k(
    const _Float16* __restrict__ inp, const _Float16* __restrict__ wA,
    const float* __restrict__ bias, _Float16* __restrict__ outp)
{
    __shared__ __align__(16) _Float16 Asm[18 * 2048];   // 73728 B

    const int tid  = threadIdx.x;
    const int lane = tid & 63;
    const int wv   = tid >> 6;
    const int l15  = lane & 15;
    const int quad = lane >> 4;

    const int zx   = blockIdx.x;          // (b*H + y)*2 + half64
    const int row  = zx >> 1;
    const int b    = row >> 7;
    const int y    = row & 127;
    const int px0  = (zx & 1) * 64 + wv * 16;

    const int sA = afrag_src(tid);

    // full preload: 18 slabs x 4 KB
#pragma unroll
    for (int s = 0; s < 18; ++s)
        gl_lds16(wA + (size_t)s * 2048 + sA, Asm + s * 2048 + tid * 8);

    // six {h, dy} B base pointers (all per-step variation is an immediate)
    const _Float16* bb[6];
#pragma unroll
    for (int h = 0; h < 2; ++h)
#pragma unroll
        for (int dy = 0; dy < 3; ++dy)
            bb[h * 3 + dy] = inp + ((size_t)(h * B_ + b) * HWP_
                                    + (size_t)(y + dy) * WP_ + px0 + l15) * 32 + quad * 8;

    floatx4 acc[4];
#pragma unroll
    for (int mf = 0; mf < 4; ++mf)
        acc[mf] = (floatx4){0.f, 0.f, 0.f, 0.f};

    __syncthreads();   // preload (all waves) visible

    const _Float16* abase = Asm + lane * 8;
#pragma unroll
    for (int ks = 0; ks < 18; ++ks) {     // ks = t*2 + h  (CH=2)
        const int t = ks >> 1, h = ks & 1;
        const int dy = t / 3, dx = t % 3;
        const half8 bfr = *(const half8*)&bb[h * 3 + dy][dx * 32];
#pragma unroll
        for (int mf = 0; mf < 4; ++mf) {
            const half8 afr = *(const half8*)&abase[ks * 2048 + mf * 512];
            acc[mf] = __builtin_amdgcn_mfma_f32_16x16x32_f16(afr, bfr, acc[mf], 0, 0, 0);
        }
    }

    // epilogue: leaky ReLU, padded slab-split f16 store
#pragma unroll
    for (int mf = 0; mf < 4; ++mf) {
        const int oc4 = mf * 16 + quad * 4;
        const float4 b4 = *(const float4*)&bias[oc4];
        half4 v4;
#pragma unroll
        for (int reg = 0; reg < 4; ++reg) {
            float r = acc[mf][reg] + ((const float*)&b4)[reg];
            r = (r >= 0.f) ? r : 0.1f * r;
            v4[reg] = (_Float16)r;
        }
        *(half4*)&outp[((size_t)((oc4 >> 5) * B_ + b) * HWP_
                        + (size_t)(y + 1) * WP_ + (px0 + l15 + 1)) * 32 + (oc4 & 31)] = v4;
    }
}

// ---------------------------------------------------------------------------
// Conv3 via f16 MFMA implicit GEMM. (unchanged from round 9: 48-oc tile,
// A slices 0..16 in LDS @ 3 blocks/CU, slice 17 in regs, barrier-free
// K-loop, zero-VALU addressing. Known 43.2 us -- control for this round.)
// ---------------------------------------------------------------------------
__global__ __launch_bounds__(256, 3) void conv3_mfma_k(
    const _Float16* __restrict__ h2p, const _Float16* __restrict__ w3A,
    const float* __restrict__ bias, const float* __restrict__ flow,
    _Float16* __restrict__ omh)
{
    __shared__ __align__(16) _Float16 Smem[17 * 1536];   // 52224 B (union)
    _Float16* Lds = Smem;                                // epilogue view

    const int tid  = threadIdx.x;
    const int lane = tid & 63;
    const int wv   = tid >> 6;       // wave id 0..3
    const int l15  = lane & 15;
    const int quad = lane >> 4;

    const int row = blockIdx.x;      // b*128 + y
    const int b   = row >> 7;
    const int y   = row & 127;
    const int m0  = blockIdx.y * 48; // oc tile base (0..384)
    const int px0 = wv * 32;

    // ---- full-K A preload, slices 0..16, fragment-major ----
#pragma unroll
    for (int r = 0; r < 13; ++r) {
        const int c = r * 256 + tid;          // global chunk id
        if (c < 17 * 192) {
            const int ks = c / 192;
            const int cl = c - ks * 192;      // chunk within slice
            const int cmf = cl >> 6, cq = (cl >> 4) & 3, ccl = cl & 15;
            gl_lds16(w3A + ((size_t)ks * OFFC_ + m0 + cmf * 16 + ccl) * 32 + cq * 8,
                     Smem + c * 8);
        }
    }

    // slice 17's A-fragments direct to registers (drained by the barrier)
    half8 Af17[3];
#pragma unroll
    for (int mf = 0; mf < 3; ++mf)
        Af17[mf] = *(const half8*)&w3A[
            ((size_t)17 * OFFC_ + m0 + mf * 16 + l15) * 32 + quad * 8];

    // six {h, dy} B base pointers; per-step variation = immediate offsets
    const _Float16* bb[6];
#pragma unroll
    for (int h = 0; h < 2; ++h)
#pragma unroll
        for (int dy = 0; dy < 3; ++dy)
            bb[h * 3 + dy] = h2p + ((size_t)(h * B_ + b) * HWP_
                                    + (size_t)(y + dy) * WP_ + px0 + l15) * 32 + quad * 8;

    floatx4 acc[3][2];
#pragma unroll
    for (int mf = 0; mf < 3; ++mf)
#pragma unroll
        for (int nf = 0; nf < 2; ++nf)
            acc[mf][nf] = (floatx4){0.f, 0.f, 0.f, 0.f};

    __syncthreads();   // preload visible (single drain before the loop)

    // ---- barrier-free K-loop, zero in-loop VALU address math ----
    const _Float16* abase = Smem + lane * 8;
#pragma unroll
    for (int ks = 0; ks < 17; ++ks) {           // ks = t*2 + h, A from LDS
        const int t = ks >> 1, h = ks & 1;
        const int dy = t / 3, dx = t % 3;
        const half8 b0 = *(const half8*)&bb[h * 3 + dy][dx * 32];
        const half8 b1 = *(const half8*)&bb[h * 3 + dy][(16 + dx) * 32];
#pragma unroll
        for (int mf = 0; mf < 3; ++mf) {
            const half8 afr = *(const half8*)&abase[ks * 1536 + mf * 512];
            acc[mf][0] = __builtin_amdgcn_mfma_f32_16x16x32_f16(afr, b0, acc[mf][0], 0, 0, 0);
            acc[mf][1] = __builtin_amdgcn_mfma_f32_16x16x32_f16(afr, b1, acc[mf][1], 0, 0, 0);
        }
    }
    {   // ks = 17: t=8 (dy=2, dx=2), h=1; A from registers
        const half8 b0 = *(const half8*)&bb[5][2 * 32];
        const half8 b1 = *(const half8*)&bb[5][(16 + 2) * 32];
#pragma unroll
        for (int mf = 0; mf < 3; ++mf) {
            acc[mf][0] = __builtin_amdgcn_mfma_f32_16x16x32_f16(Af17[mf], b0, acc[mf][0], 0, 0, 0);
            acc[mf][1] = __builtin_amdgcn_mfma_f32_16x16x32_f16(Af17[mf], b1, acc[mf][1], 0, 0, 0);
        }
    }
    __syncthreads();   // all waves done reading Smem; safe to alias Lds

    // ---- transform + stage to LDS (f16, 48 rows x 128 px, pad to 132) ----
    const bool is_off = (blockIdx.y < 6);     // block-uniform: m0 < 288
    float flY[2], flX[2];
#pragma unroll
    for (int nf = 0; nf < 2; ++nf) {
        const int px = px0 + nf * 16 + l15;
        if (is_off) {
            flY[nf] = flow[(size_t)(b * 2 + 1) * HW_ + y * W_ + px]; // slot 0 (y)
            flX[nf] = flow[(size_t)(b * 2 + 0) * HW_ + y * W_ + px]; // slot 1 (x)
        }
    }
#pragma unroll
    for (int mf = 0; mf < 3; ++mf) {
        const float4 b4 = *(const float4*)&bias[m0 + mf * 16 + quad * 4];
#pragma unroll
        for (int nf = 0; nf < 2; ++nf) {
            const int px = px0 + nf * 16 + l15;
#pragma unroll
            for (int reg = 0; reg < 4; ++reg) {
                const int ocl = mf * 16 + quad * 4 + reg;   // 0..47
                float val = acc[mf][nf][reg] + ((const float*)&b4)[reg];
                if (is_off) {                       // offset channels
                    const int slot = reg & 1;       // 0 = y, 1 = x
                    const float fl = slot ? flX[nf] : flY[nf];
                    const float e = __expf(2.f * val);      // tanh via exp
                    val = 10.f * (1.f - __fdividef(2.f, e + 1.f)) + fl;
                } else {                            // mask channels: sigmoid
                    val = __fdividef(1.f, 1.f + __expf(-val));
                }
                Lds[ocl * 132 + px] = (_Float16)val;
            }
        }
    }
    __syncthreads();   // LDS read-only hereafter

    // ---- contiguous f16 copy-out: 48 plane-rows x 128 px ----
#pragma unroll
    for (int it = 0; it < 6; ++it) {
        const int j4 = it * 256 + tid;
        const int r  = j4 >> 5;          // 0..47
        const int c4 = j4 & 31;          // half4 col
        const int oc = m0 + r;
        int g, k, slot;
        if (oc < 2 * DG_ * KK_) {
            g = oc / 18;
            const int rem = oc - g * 18;
            k = rem >> 1;
            slot = rem & 1;
        } else {
            const int c = oc - 2 * DG_ * KK_;
            g = c / 9;
            k = c - g * 9;
            slot = 2;
        }
        const half4 hv = *(const half4*)&Lds[r * 132 + c4 * 4];
        *(half4*)&omh[((size_t)((b * DG_ * KK_ + g * KK_ + k) * 3 + slot)) * HW_
                      + y * W_ + c4 * 4] = hv;
    }
}

// ---------------------------------------------------------------------------
// Phase A: bilinear gather, PIXEL-MAJOR lanes. Thread = one pixel for a
// fixed (b,k); loops g=0..15 in registers.
// v9: omh loads for ALL 16 g hoisted into one unrolled burst (48 loads in
// flight) before any tap math -- breaks the load->compute->load dependency
// chain that serialized the kernel at tiny VGPR budgets.
// ---------------------------------------------------------------------------
__global__ __launch_bounds__(256, 2) void gather_k(
    const _Float16* __restrict__ xg, const _Float16* __restrict__ omh,
    _Float16* __restrict__ valh)
{
    const int tid = threadIdx.x;
    const int pix = blockIdx.x * 256 + tid;
    const int zy  = blockIdx.y;               // b*9 + k
    const int b   = zy / KK_;
    const int k   = zy - b * KK_;
    const int yp  = pix >> 7;
    const int xp  = pix & (W_ - 1);
    const float fy = (float)(yp + (k / 3) - 1);
    const float fx = (float)(xp + (k % 3) - 1);

    // burst-load all offsets/masks (static indices; 48 loads in flight)
    float oyA[16], oxA[16], mA[16];
#pragma unroll
    for (int g = 0; g < DG_; ++g) {
        const size_t obase = ((size_t)((b * DG_ + g) * KK_ + k) * 3) * HW_ + pix;
        oyA[g] = (float)omh[obase];
        oxA[g] = (float)omh[obase + HW_];
        mA[g]  = (float)omh[obase + 2 * HW_];
    }

    half4 rec[16];
#pragma unroll
    for (int g = 0; g < DG_; ++g) {
        const float py = fy + oyA[g];
        const float px = fx + oxA[g];
        const float y0f = floorf(py);
        const float x0f = floorf(px);
        const float wy = py - y0f;
        const float wx = px - x0f;
        const int y0 = (int)y0f, x0 = (int)x0f;
        const int y1 = y0 + 1,  x1 = x0 + 1;
        const bool vy0 = ((unsigned)y0 < (unsigned)H_);
        const bool vy1 = ((unsigned)y1 < (unsigned)H_);
        const bool vx0 = ((unsigned)x0 < (unsigned)W_);
        const bool vx1 = ((unsigned)x1 < (unsigned)W_);
        const float w00 = vy0 && vx0 ? (1.f - wy) * (1.f - wx) : 0.f;
        const float w01 = vy0 && vx1 ? (1.f - wy) * wx         : 0.f;
        const float w10 = vy1 && vx0 ? wy * (1.f - wx)         : 0.f;
        const float w11 = vy1 && vx1 ? wy * wx                 : 0.f;
        const int i00 = (vy0 && vx0) ? y0 * W_ + x0 : 0;
        const int i01 = (vy0 && vx1) ? y0 * W_ + x1 : 0;
        const int i10 = (vy1 && vx0) ? y1 * W_ + x0 : 0;
        const int i11 = (vy1 && vx1) ? y1 * W_ + x1 : 0;

        const _Float16* xb = xg + (size_t)(b * DG_ + g) * HW_ * 4;
        const half4 p00 = *(const half4*)&xb[(size_t)i00 * 4];
        const half4 p01 = *(const half4*)&xb[(size_t)i01 * 4];
        const half4 p10 = *(const half4*)&xb[(size_t)i10 * 4];
        const half4 p11 = *(const half4*)&xb[(size_t)i11 * 4];

        half4 v4;
#pragma unroll
        for (int c = 0; c < CG_; ++c) {
            float v = w00 * (float)p00[c] + w01 * (float)p01[c]
                    + w10 * (float)p10[c] + w11 * (float)p11[c];
            v4[c] = (_Float16)(v * mA[g]);
        }
        rec[g] = v4;
    }

    // write slabs s = 2k (g 0..7) and 2k+1 (g 8..15): 64 B each, contiguous
    _Float16* r0 = &valh[((size_t)((2 * k) * B_ + b) * HW_ + pix) * 32];
    _Float16* r1 = &valh[((size_t)((2 * k + 1) * B_ + b) * HW_ + pix) * 32];
#pragma unroll
    for (int j = 0; j < 4; ++j) {
        half8 w0, w1;
#pragma unroll
        for (int c = 0; c < 4; ++c) {
            w0[c]     = rec[2 * j][c];
            w0[c + 4] = rec[2 * j + 1][c];
            w1[c]     = rec[8 + 2 * j][c];
            w1[c + 4] = rec[9 + 2 * j][c];
        }
        *(half8*)&r0[j * 8] = w0;
        *(half8*)&r1[j * 8] = w1;
    }
}

// ---------------------------------------------------------------------------
// Phase B: einsum via f16 MFMA. Wave = 16 px x 64 oc (mf=4).
// FULL A preload (72 KB), barrier-free 18-step loop, epilogue aliases A.
// ---------------------------------------------------------------------------
__global__ __launch_bounds__(256, 2) void einsum_mfma_k(
    const _Float16* __restrict__ valh, const _Float16* __restrict__ wkA,
    float* __restrict__ out)
{
    __shared__ __align__(16) _Float16 Smem[18 * 2048];  // 73728 B (union)
    float* Lds = (float*)Smem;                          // epilogue view

    const int tid  = threadIdx.x;
    const int lane = tid & 63;
    const int wv   = tid >> 6;
    const int l15  = lane & 15;
    const int quad = lane >> 4;

    const int pixg0 = blockIdx.x * 64 + wv * 16;    // global pixel (b*HW+pix)
    const int b     = pixg0 >> 14;
    const int pix0  = pixg0 & (HW_ - 1);

    const int sA = afrag_src(tid);

    // full preload: 18 slabs x 4 KB
#pragma unroll
    for (int s = 0; s < 18; ++s)
        gl_lds16(wkA + (size_t)s * 2048 + sA, Smem + s * 2048 + tid * 8);

    floatx4 acc[4];
#pragma unroll
    for (int mf = 0; mf < 4; ++mf)
        acc[mf] = (floatx4){0.f, 0.f, 0.f, 0.f};

    half8 Bf[2];
    Bf[0] = *(const half8*)&valh[((size_t)(0 * B_ + b) * HW_ + pix0 + l15) * 32 + quad * 8];
    __syncthreads();   // preload visible

#pragma unroll
    for (int s = 0; s < 18; ++s) {
        const int cur = s & 1, nxt = cur ^ 1;
        if (s < 17) {
            const int s1 = s + 1;
            Bf[nxt] = *(const half8*)&valh[
                ((size_t)(s1 * B_ + b) * HW_ + pix0 + l15) * 32 + quad * 8];
        }
        const _Float16* abase = Smem + s * 2048 + lane * 8;
#pragma unroll
        for (int mf = 0; mf < 4; ++mf) {
            const half8 afr = *(const half8*)&abase[mf * 512];
            acc[mf] = __builtin_amdgcn_mfma_f32_16x16x32_f16(afr, Bf[cur], acc[mf], 0, 0, 0);
        }
    }
    __syncthreads();   // all waves done reading A; safe to alias

    // ---- stage 64 oc x 64 px tile to LDS ----
    const int pxl = wv * 16 + l15;                  // 0..63 block-local pixel
#pragma unroll
    for (int mf = 0; mf < 4; ++mf)
#pragma unroll
        for (int reg = 0; reg < 4; ++reg)
            Lds[(mf * 16 + quad * 4 + reg) * 68 + pxl] = acc[mf][reg];
    __syncthreads();   // LDS read-only hereafter

    // ---- coalesced copy-out: 64 oc-rows x 64 px (16 float4 per row) ----
    const int pixb = blockIdx.x * 64 & (HW_ - 1);   // block-base pixel
#pragma unroll
    for (int it = 0; it < 4; ++it) {
        const int j4 = it * 256 + tid;
        const int r  = j4 >> 4;                     // oc 0..63
        const int c4 = j4 & 15;                     // float4 col
        float4 v;
        v.x = Lds[r * 68 + c4 * 4 + 0];
        v.y = Lds[r * 68 + c4 * 4 + 1];
        v.z = Lds[r * 68 + c4 * 4 + 2];
        v.w = Lds[r * 68 + c4 * 4 + 3];
        *(float4*)&out[((size_t)(b * C_ + r)) * HW_ + pixb + c4 * 4] = v;
    }
}

// ---------------------------------------------------------------------------
extern "C" void kernel_launch(void* const* d_in, const int* in_sizes, int n_in,
                              void* d_out, int out_size, void* d_ws, size_t ws_size,
                              hipStream_t stream)
{
    const float* x    = (const float*)d_in[0];
    const float* ef   = (const float*)d_in[1];
    const float* flow = (const float*)d_in[2];
    const float* w1   = (const float*)d_in[3];
    const float* b1   = (const float*)d_in[4];
    const float* w2   = (const float*)d_in[5];
    const float* b2   = (const float*)d_in[6];
    const float* w3   = (const float*)d_in[7];
    const float* b3   = (const float*)d_in[8];
    const float* wk   = (const float*)d_in[9];
    float* out = (float*)d_out;

    // Workspace (half slots):
    //   omh 14,155,776 | valh 18,874,368 | ef_p 4*B*HWP*32 = 4,326,400
    //   xg 2,097,152 | h1p 2*B*HWP*32 = 2,163,200 | h2p 2,163,200
    //   w1A 73,728 | w2A 36,864 | w3A 248,832 | wkA 36,864
    _Float16* omh  = (_Float16*)d_ws;
    _Float16* valh = omh + (size_t)B_ * OFFC_ * HW_;
    _Float16* ef_p = valh + (size_t)18 * B_ * HW_ * 32;
    _Float16* xg   = ef_p + (size_t)4 * B_ * HWP_ * 32;
    _Float16* h1p  = xg + (size_t)B_ * HW_ * 64;
    _Float16* h2p  = h1p + (size_t)2 * B_ * HWP_ * 32;
    _Float16* w1A  = h2p + (size_t)2 * B_ * HWP_ * 32;
    _Float16* w2A  = w1A + 64 * 128 * 9;
    _Float16* w3A  = w2A + 64 * 64 * 9;
    _Float16* wkA  = w3A + OFFC_ * 64 * 9;

    // Zero the padded buffers (borders must be 0; interiors overwritten).
    hipMemsetAsync(ef_p, 0, (size_t)4 * B_ * HWP_ * 32 * 2, stream);
    hipMemsetAsync(h1p, 0, (size_t)2 * B_ * HWP_ * 32 * 2, stream);
    hipMemsetAsync(h2p, 0, (size_t)2 * B_ * HWP_ * 32 * 2, stream);

    prep_wA_k<64, 128><<<dim3((64 * 128 * 9 + 255) / 256), 256, 0, stream>>>(w1, w1A);
    prep_wA_k<64, 64><<<dim3((64 * 64 * 9 + 255) / 256), 256, 0, stream>>>(w2, w2A);
    prep_wA_k<OFFC_, 64><<<dim3((OFFC_ * 64 * 9 + 255) / 256), 256, 0, stream>>>(w3, w3A);
    prep_wkA_k<<<dim3((18 * 64 * 32 + 255) / 256), 256, 0, stream>>>(wk, wkA);
    nchw2slabpad_f16_k<128><<<dim3(HW_ / 256, B_), 256, 0, stream>>>(ef, ef_p);
    nchw2gx_f16_k<<<dim3(HW_ / 256, B_), 256, 0, stream>>>(x, xg);

    conv1_mfma_k<<<dim3(B_ * H_ * 2), 256, 0, stream>>>(ef_p, w1A, b1, h1p);
    conv2_mfma_k<<<dim3(B_ * H_ * 2), 256, 0, stream>>>(h1p, w2A, b2, h2p);
    conv3_mfma_k<<<dim3(B_ * H_, 9), 256, 0, stream>>>(h2p, w3A, b3, flow, omh);

    gather_k<<<dim3(HW_ / 256, B_ * KK_), 256, 0, stream>>>(xg, omh, valh);
    einsum_mfma_k<<<dim3(B_ * HW_ / 64), 256, 0, stream>>>(valh, wkA, out);
}

// Round 11
// 189.280 us; speedup vs baseline: 1.1798x; 1.0897x over previous
//
#include <hip/hip_runtime.h>
#include <math.h>

// Problem constants (fixed by setup_inputs)
constexpr int B_   = 2;
constexpr int C_   = 64;
constexpr int H_   = 128;
constexpr int W_   = 128;
constexpr int HW_  = H_ * W_;
constexpr int DG_  = 16;   // deformable groups
constexpr int KK_  = 9;    // 3x3 taps
constexpr int CG_  = 4;    // channels per group = C/DG
constexpr int OFFC_ = 3 * KK_ * DG_;  // 432
constexpr int R_   = C_ * KK_;        // 576 reduction length
constexpr int WP_  = 130;             // padded width/height
constexpr int HWP_ = WP_ * WP_;       // 16900 padded pixels

typedef _Float16 half8 __attribute__((ext_vector_type(8)));  // 8 f16 = 4 VGPR
typedef _Float16 half4 __attribute__((ext_vector_type(4)));  // 8-byte load/store
typedef float floatx4 __attribute__((ext_vector_type(4)));   // MFMA acc

// Async global->LDS DMA, 16 B per lane. LDS dest is wave-uniform base +
// lane*16 (m104); every call site passes exactly that shape.
__device__ __forceinline__ void gl_lds16(const _Float16* g, _Float16* l)
{
    __builtin_amdgcn_global_load_lds(
        (const __attribute__((address_space(1))) void*)g,
        (__attribute__((address_space(3))) void*)l, 16, 0, 0);
}

// Fragment-major A staging: LDS chunk c (16 B) holds the data fragment
// (mf = c>>6) needs at lane (c&63): global f16 index within the K-slice.
__device__ __forceinline__ int afrag_src(int c)
{
    const int cmf = c >> 6, cq = (c >> 4) & 3, cl = c & 15;
    return (cmf * 16 + cl) * 32 + cq * 8;
}

// ---------------------------------------------------------------------------
// MERGED SETUP KERNEL (v11): all weight preps + both layout transposes +
// border-only zeroing of padded buffers, dispatched by blockIdx.x range.
// Replaces 6 tiny kernels + 3 hipMemsetAsync -> 1 launch. All sub-tasks are
// independent (disjoint outputs, input-only reads).
// Block ranges:
//   [0,288)      prep w1A   (64x128 conv1 weights,  j < 73728)
//   [288,432)    prep w2A   (64x64,                 j < 36864)
//   [432,1404)   prep w3A   (432x64,                j < 248832)
//   [1404,1548)  prep wkA   (einsum weights,        j < 36864)
//   [1548,1676)  ef -> ef_p padded slab-split f16 (128 ch)
//   [1676,1804)  x  -> xg   per-group planes f16
//   [1804,1837)  border zero: 16 planes x 516 border px x 32 ch
// ---------------------------------------------------------------------------
constexpr int SR0 = 288, SR1 = 432, SR2 = 1404, SR3 = 1548;
constexpr int SR4 = 1676, SR5 = 1804, SR6 = 1837;

__global__ __launch_bounds__(256) void setup_k(
    const float* __restrict__ x,  const float* __restrict__ ef,
    const float* __restrict__ w1, const float* __restrict__ w2,
    const float* __restrict__ w3, const float* __restrict__ wk,
    _Float16* __restrict__ w1A, _Float16* __restrict__ w2A,
    _Float16* __restrict__ w3A, _Float16* __restrict__ wkA,
    _Float16* __restrict__ ef_p, _Float16* __restrict__ xg,
    _Float16* __restrict__ h1p,  _Float16* __restrict__ h2p)
{
    const int bid = blockIdx.x;
    const int tid = threadIdx.x;

    if (bid < SR0) {                       // ---- prep w1A: OC=64, CIN=128
        constexpr int OC = 64, CH = 4;
        const int j = bid * 256 + tid;
        if (j >= 9 * CH * OC * 32) return;
        const int slab = j / (OC * 32);
        const int rem  = j - slab * (OC * 32);
        const int oc   = rem >> 5;
        const int jj   = rem & 31;
        const int t    = slab / CH;
        const int h    = slab - t * CH;
        const int ic   = h * 32 + jj;
        w1A[j] = (_Float16)w1[(size_t)oc * (128 * 9) + ic * 9 + t];
    } else if (bid < SR1) {                // ---- prep w2A: OC=64, CIN=64
        constexpr int OC = 64, CH = 2;
        const int j = (bid - SR0) * 256 + tid;
        if (j >= 9 * CH * OC * 32) return;
        const int slab = j / (OC * 32);
        const int rem  = j - slab * (OC * 32);
        const int oc   = rem >> 5;
        const int jj   = rem & 31;
        const int t    = slab / CH;
        const int h    = slab - t * CH;
        const int ic   = h * 32 + jj;
        w2A[j] = (_Float16)w2[(size_t)oc * (64 * 9) + ic * 9 + t];
    } else if (bid < SR2) {                // ---- prep w3A: OC=432, CIN=64
        constexpr int OC = OFFC_, CH = 2;
        const int j = (bid - SR1) * 256 + tid;
        if (j >= 9 * CH * OC * 32) return;
        const int slab = j / (OC * 32);
        const int rem  = j - slab * (OC * 32);
        const int oc   = rem >> 5;
        const int jj   = rem & 31;
        const int t    = slab / CH;
        const int h    = slab - t * CH;
        const int ic   = h * 32 + jj;
        w3A[j] = (_Float16)w3[(size_t)oc * (64 * 9) + ic * 9 + t];
    } else if (bid < SR3) {                // ---- prep wkA
        const int j = (bid - SR2) * 256 + tid;
        if (j >= 18 * 64 * 32) return;
        const int s   = j >> 11;
        const int rem = j & 2047;
        const int oc  = rem >> 5;
        const int jj  = rem & 31;
        const int k   = s >> 1;
        const int gc  = (s & 1) * 32 + jj;
        wkA[j] = (_Float16)wk[(size_t)oc * R_ + gc * 9 + k];
    } else if (bid < SR4) {                // ---- ef -> ef_p (padded slabs)
        const int lb  = bid - SR3;         // 0..127
        const int b   = lb >> 6;
        const int pix = (lb & 63) * 256 + tid;
        const int yp  = pix >> 7;
        const int xp  = pix & (W_ - 1);
        const float* ib = ef + (size_t)b * 128 * HW_ + pix;
#pragma unroll
        for (int c0 = 0; c0 < 128; c0 += 8) {
            half8 v;
#pragma unroll
            for (int j = 0; j < 8; ++j)
                v[j] = (_Float16)ib[(size_t)(c0 + j) * HW_];
            const int slab = c0 >> 5;
            *(half8*)&ef_p[((size_t)(slab * B_ + b) * HWP_
                            + (size_t)(yp + 1) * WP_ + (xp + 1)) * 32 + (c0 & 31)] = v;
        }
    } else if (bid < SR5) {                // ---- x -> xg (per-group planes)
        const int lb  = bid - SR4;         // 0..127
        const int b   = lb >> 6;
        const int pix = (lb & 63) * 256 + tid;
        const float* ib = x + (size_t)b * C_ * HW_ + pix;
#pragma unroll
        for (int g = 0; g < DG_; ++g) {
            half4 v;
#pragma unroll
            for (int c = 0; c < 4; ++c)
                v[c] = (_Float16)ib[(size_t)(g * 4 + c) * HW_];
            *(half4*)&xg[((size_t)(b * DG_ + g) * HW_ + pix) * 4] = v;
        }
    } else {                               // ---- border zero (16 planes)
        const int idx = (bid - SR5) * 256 + tid;   // plane*516 + p
        if (idx >= 16 * 516) return;
        const int plane = idx / 516;
        const int p     = idx - plane * 516;
        int yp, xp;
        if (p < 130)      { yp = 0;            xp = p; }
        else if (p < 260) { yp = 129;          xp = p - 130; }
        else if (p < 388) { yp = 1 + (p - 260); xp = 0; }
        else              { yp = 1 + (p - 388); xp = 129; }
        _Float16* base;
        if (plane < 8)       base = ef_p + (size_t)plane * HWP_ * 32;
        else if (plane < 12) base = h1p + (size_t)(plane - 8) * HWP_ * 32;
        else                 base = h2p + (size_t)(plane - 12) * HWP_ * 32;
        _Float16* dst = base + ((size_t)yp * WP_ + xp) * 32;
        const half8 z = (half8){0, 0, 0, 0, 0, 0, 0, 0};
#pragma unroll
        for (int j = 0; j < 4; ++j)
            *(half8*)&dst[j * 8] = z;
    }
}

// ---------------------------------------------------------------------------
// Conv1 (128 -> 64) via f16 MFMA. Wave tile = 64 oc x 16 px (mf=4).
// Split-K two-phase FULL preload; zero-VALU in-loop addressing.
// ---------------------------------------------------------------------------
__global__ __launch_bounds__(256, 2) void conv1_mfma_k(
    const _Float16* __restrict__ inp, const _Float16* __restrict__ wA,
    const float* __restrict__ bias, _Float16* __restrict__ outp)
{
    __shared__ __align__(16) _Float16 Asm[18 * 2048];   // 73728 B

    const int tid  = threadIdx.x;
    const int lane = tid & 63;
    const int wv   = tid >> 6;
    const int l15  = lane & 15;
    const int quad = lane >> 4;

    const int zx   = blockIdx.x;          // (b*H + y)*2 + half64
    const int row  = zx >> 1;
    const int b    = row >> 7;
    const int y    = row & 127;
    const int px0  = (zx & 1) * 64 + wv * 16;

    const int sA = afrag_src(tid);        // global f16 offset for my chunk

    // twelve {h 0..3, dy 0..2} B base pointers; per-step delta = immediate
    const _Float16* bb[12];
#pragma unroll
    for (int h = 0; h < 4; ++h)
#pragma unroll
        for (int dy = 0; dy < 3; ++dy)
            bb[h * 3 + dy] = inp + ((size_t)(h * B_ + b) * HWP_
                                    + (size_t)(y + dy) * WP_ + px0 + l15) * 32 + quad * 8;

    floatx4 acc[4];
#pragma unroll
    for (int mf = 0; mf < 4; ++mf)
        acc[mf] = (floatx4){0.f, 0.f, 0.f, 0.f};

    // ---- phase 0: preload slabs 0..17 ----
#pragma unroll
    for (int s = 0; s < 18; ++s)
        gl_lds16(wA + (size_t)s * 2048 + sA, Asm + s * 2048 + tid * 8);
    __syncthreads();   // staged + visible

    const _Float16* abase = Asm + lane * 8;
#pragma unroll
    for (int ks = 0; ks < 18; ++ks) {     // ks = t*4 + h  (CH=4)
        const int t = ks >> 2, h = ks & 3;
        const int dy = t / 3, dx = t % 3;
        const half8 bfr = *(const half8*)&bb[h * 3 + dy][dx * 32];
#pragma unroll
        for (int mf = 0; mf < 4; ++mf) {
            const half8 afr = *(const half8*)&abase[ks * 2048 + mf * 512];
            acc[mf] = __builtin_amdgcn_mfma_f32_16x16x32_f16(afr, bfr, acc[mf], 0, 0, 0);
        }
    }
    __syncthreads();   // all waves done reading phase-0 A

    // ---- phase 1: re-stage slabs 18..35 into the same LDS ----
#pragma unroll
    for (int s = 0; s < 18; ++s)
        gl_lds16(wA + (size_t)(18 + s) * 2048 + sA, Asm + s * 2048 + tid * 8);
    __syncthreads();   // staged + visible

#pragma unroll
    for (int ks = 18; ks < 36; ++ks) {
        const int t = ks >> 2, h = ks & 3;
        const int dy = t / 3, dx = t % 3;
        const half8 bfr = *(const half8*)&bb[h * 3 + dy][dx * 32];
#pragma unroll
        for (int mf = 0; mf < 4; ++mf) {
            const half8 afr = *(const half8*)&abase[(ks - 18) * 2048 + mf * 512];
            acc[mf] = __builtin_amdgcn_mfma_f32_16x16x32_f16(afr, bfr, acc[mf], 0, 0, 0);
        }
    }

    // epilogue: leaky ReLU, padded slab-split f16 store (8 B/lane x 4 tiles)
#pragma unroll
    for (int mf = 0; mf < 4; ++mf) {
        const int oc4 = mf * 16 + quad * 4;        // first of 4 output chans
        const float4 b4 = *(const float4*)&bias[oc4];
        half4 v4;
#pragma unroll
        for (int reg = 0; reg < 4; ++reg) {
            float r = acc[mf][reg] + ((const float*)&b4)[reg];
            r = (r >= 0.f) ? r : 0.1f * r;
            v4[reg] = (_Float16)r;
        }
        *(half4*)&outp[((size_t)((oc4 >> 5) * B_ + b) * HWP_
                        + (size_t)(y + 1) * WP_ + (px0 + l15 + 1)) * 32 + (oc4 & 31)] = v4;
    }
}

// ---------------------------------------------------------------------------
// Conv2 (64 -> 64) via f16 MFMA. Wave tile = 64 oc x 16 px (mf=4).
// FULL A preload (72 KB LDS), barrier-free 18-step K-loop, zero-VALU
// in-loop addressing (six {h,dy} base pointers, immediate offsets).
// ---------------------------------------------------------------------------
__global__ __launch_bounds__(256, 2) void conv2_mfma_k(
    const _Float16* __restrict__ inp, const _Float16* __restrict__ wA,
    const float* __restrict__ bias, _Float16* __restrict__ outp)
{
    __shared__ __align__(16) _Float16 Asm[18 * 2048];   // 73728 B

    const int tid  = threadIdx.x;
    const int lane = tid & 63;
    const int wv   = tid >> 6;
    const int l15  = lane & 15;
    const int quad = lane >> 4;

    const int zx   = blockIdx.x;          // (b*H + y)*2 + half64
    const int row  = zx >> 1;
    const int b    = row >> 7;
    const int y    = row & 127;
    const int px0  = (zx & 1) * 64 + wv * 16;

    const int sA = afrag_src(tid);

    // full preload: 18 slabs x 4 KB
#pragma unroll
    for (int s = 0; s < 18; ++s)
        gl_lds16(wA + (size_t)s * 2048 + sA, Asm + s * 2048 + tid * 8);

    // six {h, dy} B base pointers (all per-step variation is an immediate)
    const _Float16* bb[6];
#pragma unroll
    for (int h = 0; h < 2; ++h)
#pragma unroll
        for (int dy = 0; dy < 3; ++dy)
            bb[h * 3 + dy] = inp + ((size_t)(h * B_ + b) * HWP_
                                    + (size_t)(y + dy) * WP_ + px0 + l15) * 32 + quad * 8;

    floatx4 acc[4];
#pragma unroll
    for (int mf = 0; mf < 4; ++mf)
        acc[mf] = (floatx4){0.f, 0.f, 0.f, 0.f};

    __syncthreads();   // preload (all waves) visible

    const _Float16* abase = Asm + lane * 8;
#pragma unroll
    for (int ks = 0; ks < 18; ++ks) {     // ks = t*2 + h  (CH=2)
        const int t = ks >> 1, h = ks & 1;
        const int dy = t / 3, dx = t % 3;
        const half8 bfr = *(const half8*)&bb[h * 3 + dy][dx * 32];
#pragma unroll
        for (int mf = 0; mf < 4; ++mf) {
            const half8 afr = *(const half8*)&abase[ks * 2048 + mf * 512];
            acc[mf] = __builtin_amdgcn_mfma_f32_16x16x32_f16(afr, bfr, acc[mf], 0, 0, 0);
        }
    }

    // epilogue: leaky ReLU, padded slab-split f16 store
#pragma unroll
    for (int mf = 0; mf < 4; ++mf) {
        const int oc4 = mf * 16 + quad * 4;
        const float4 b4 = *(const float4*)&bias[oc4];
        half4 v4;
#pragma unroll
        for (int reg = 0; reg < 4; ++reg) {
            float r = acc[mf][reg] + ((const float*)&b4)[reg];
            r = (r >= 0.f) ? r : 0.1f * r;
            v4[reg] = (_Float16)r;
        }
        *(half4*)&outp[((size_t)((oc4 >> 5) * B_ + b) * HWP_
                        + (size_t)(y + 1) * WP_ + (px0 + l15 + 1)) * 32 + (oc4 & 31)] = v4;
    }
}

// ---------------------------------------------------------------------------
// Conv3 via f16 MFMA implicit GEMM. (unchanged: control @ ~43.5 us)
// ---------------------------------------------------------------------------
__global__ __launch_bounds__(256, 3) void conv3_mfma_k(
    const _Float16* __restrict__ h2p, const _Float16* __restrict__ w3A,
    const float* __restrict__ bias, const float* __restrict__ flow,
    _Float16* __restrict__ omh)
{
    __shared__ __align__(16) _Float16 Smem[17 * 1536];   // 52224 B (union)
    _Float16* Lds = Smem;                                // epilogue view

    const int tid  = threadIdx.x;
    const int lane = tid & 63;
    const int wv   = tid >> 6;       // wave id 0..3
    const int l15  = lane & 15;
    const int quad = lane >> 4;

    const int row = blockIdx.x;      // b*128 + y
    const int b   = row >> 7;
    const int y   = row & 127;
    const int m0  = blockIdx.y * 48; // oc tile base (0..384)
    const int px0 = wv * 32;

    // ---- full-K A preload, slices 0..16, fragment-major ----
#pragma unroll
    for (int r = 0; r < 13; ++r) {
        const int c = r * 256 + tid;          // global chunk id
        if (c < 17 * 192) {
            const int ks = c / 192;
            const int cl = c - ks * 192;      // chunk within slice
            const int cmf = cl >> 6, cq = (cl >> 4) & 3, ccl = cl & 15;
            gl_lds16(w3A + ((size_t)ks * OFFC_ + m0 + cmf * 16 + ccl) * 32 + cq * 8,
                     Smem + c * 8);
        }
    }

    // slice 17's A-fragments direct to registers (drained by the barrier)
    half8 Af17[3];
#pragma unroll
    for (int mf = 0; mf < 3; ++mf)
        Af17[mf] = *(const half8*)&w3A[
            ((size_t)17 * OFFC_ + m0 + mf * 16 + l15) * 32 + quad * 8];

    // six {h, dy} B base pointers; per-step variation = immediate offsets
    const _Float16* bb[6];
#pragma unroll
    for (int h = 0; h < 2; ++h)
#pragma unroll
        for (int dy = 0; dy < 3; ++dy)
            bb[h * 3 + dy] = h2p + ((size_t)(h * B_ + b) * HWP_
                                    + (size_t)(y + dy) * WP_ + px0 + l15) * 32 + quad * 8;

    floatx4 acc[3][2];
#pragma unroll
    for (int mf = 0; mf < 3; ++mf)
#pragma unroll
        for (int nf = 0; nf < 2; ++nf)
            acc[mf][nf] = (floatx4){0.f, 0.f, 0.f, 0.f};

    __syncthreads();   // preload visible (single drain before the loop)

    // ---- barrier-free K-loop, zero in-loop VALU address math ----
    const _Float16* abase = Smem + lane * 8;
#pragma unroll
    for (int ks = 0; ks < 17; ++ks) {           // ks = t*2 + h, A from LDS
        const int t = ks >> 1, h = ks & 1;
        const int dy = t / 3, dx = t % 3;
        const half8 b0 = *(const half8*)&bb[h * 3 + dy][dx * 32];
        const half8 b1 = *(const half8*)&bb[h * 3 + dy][(16 + dx) * 32];
#pragma unroll
        for (int mf = 0; mf < 3; ++mf) {
            const half8 afr = *(const half8*)&abase[ks * 1536 + mf * 512];
            acc[mf][0] = __builtin_amdgcn_mfma_f32_16x16x32_f16(afr, b0, acc[mf][0], 0, 0, 0);
            acc[mf][1] = __builtin_amdgcn_mfma_f32_16x16x32_f16(afr, b1, acc[mf][1], 0, 0, 0);
        }
    }
    {   // ks = 17: t=8 (dy=2, dx=2), h=1; A from registers
        const half8 b0 = *(const half8*)&bb[5][2 * 32];
        const half8 b1 = *(const half8*)&bb[5][(16 + 2) * 32];
#pragma unroll
        for (int mf = 0; mf < 3; ++mf) {
            acc[mf][0] = __builtin_amdgcn_mfma_f32_16x16x32_f16(Af17[mf], b0, acc[mf][0], 0, 0, 0);
            acc[mf][1] = __builtin_amdgcn_mfma_f32_16x16x32_f16(Af17[mf], b1, acc[mf][1], 0, 0, 0);
        }
    }
    __syncthreads();   // all waves done reading Smem; safe to alias Lds

    // ---- transform + stage to LDS (f16, 48 rows x 128 px, pad to 132) ----
    const bool is_off = (blockIdx.y < 6);     // block-uniform: m0 < 288
    float flY[2], flX[2];
#pragma unroll
    for (int nf = 0; nf < 2; ++nf) {
        const int px = px0 + nf * 16 + l15;
        if (is_off) {
            flY[nf] = flow[(size_t)(b * 2 + 1) * HW_ + y * W_ + px]; // slot 0 (y)
            flX[nf] = flow[(size_t)(b * 2 + 0) * HW_ + y * W_ + px]; // slot 1 (x)
        }
    }
#pragma unroll
    for (int mf = 0; mf < 3; ++mf) {
        const float4 b4 = *(const float4*)&bias[m0 + mf * 16 + quad * 4];
#pragma unroll
        for (int nf = 0; nf < 2; ++nf) {
            const int px = px0 + nf * 16 + l15;
#pragma unroll
            for (int reg = 0; reg < 4; ++reg) {
                const int ocl = mf * 16 + quad * 4 + reg;   // 0..47
                float val = acc[mf][nf][reg] + ((const float*)&b4)[reg];
                if (is_off) {                       // offset channels
                    const int slot = reg & 1;       // 0 = y, 1 = x
                    const float fl = slot ? flX[nf] : flY[nf];
                    const float e = __expf(2.f * val);      // tanh via exp
                    val = 10.f * (1.f - __fdividef(2.f, e + 1.f)) + fl;
                } else {                            // mask channels: sigmoid
                    val = __fdividef(1.f, 1.f + __expf(-val));
                }
                Lds[ocl * 132 + px] = (_Float16)val;
            }
        }
    }
    __syncthreads();   // LDS read-only hereafter

    // ---- contiguous f16 copy-out: 48 plane-rows x 128 px ----
#pragma unroll
    for (int it = 0; it < 6; ++it) {
        const int j4 = it * 256 + tid;
        const int r  = j4 >> 5;          // 0..47
        const int c4 = j4 & 31;          // half4 col
        const int oc = m0 + r;
        int g, k, slot;
        if (oc < 2 * DG_ * KK_) {
            g = oc / 18;
            const int rem = oc - g * 18;
            k = rem >> 1;
            slot = rem & 1;
        } else {
            const int c = oc - 2 * DG_ * KK_;
            g = c / 9;
            k = c - g * 9;
            slot = 2;
        }
        const half4 hv = *(const half4*)&Lds[r * 132 + c4 * 4];
        *(half4*)&omh[((size_t)((b * DG_ * KK_ + g * KK_ + k) * 3 + slot)) * HW_
                      + y * W_ + c4 * 4] = hv;
    }
}

// ---------------------------------------------------------------------------
// Phase A: bilinear gather, PIXEL-MAJOR lanes; omh loads burst-hoisted.
// ---------------------------------------------------------------------------
__global__ __launch_bounds__(256, 2) void gather_k(
    const _Float16* __restrict__ xg, const _Float16* __restrict__ omh,
    _Float16* __restrict__ valh)
{
    const int tid = threadIdx.x;
    const int pix = blockIdx.x * 256 + tid;
    const int zy  = blockIdx.y;               // b*9 + k
    const int b   = zy / KK_;
    const int k   = zy - b * KK_;
    const int yp  = pix >> 7;
    const int xp  = pix & (W_ - 1);
    const float fy = (float)(yp + (k / 3) - 1);
    const float fx = (float)(xp + (k % 3) - 1);

    // burst-load all offsets/masks (static indices; 48 loads in flight)
    float oyA[16], oxA[16], mA[16];
#pragma unroll
    for (int g = 0; g < DG_; ++g) {
        const size_t obase = ((size_t)((b * DG_ + g) * KK_ + k) * 3) * HW_ + pix;
        oyA[g] = (float)omh[obase];
        oxA[g] = (float)omh[obase + HW_];
        mA[g]  = (float)omh[obase + 2 * HW_];
    }

    half4 rec[16];
#pragma unroll
    for (int g = 0; g < DG_; ++g) {
        const float py = fy + oyA[g];
        const float px = fx + oxA[g];
        const float y0f = floorf(py);
        const float x0f = floorf(px);
        const float wy = py - y0f;
        const float wx = px - x0f;
        const int y0 = (int)y0f, x0 = (int)x0f;
        const int y1 = y0 + 1,  x1 = x0 + 1;
        const bool vy0 = ((unsigned)y0 < (unsigned)H_);
        const bool vy1 = ((unsigned)y1 < (unsigned)H_);
        const bool vx0 = ((unsigned)x0 < (unsigned)W_);
        const bool vx1 = ((unsigned)x1 < (unsigned)W_);
        const float w00 = vy0 && vx0 ? (1.f - wy) * (1.f - wx) : 0.f;
        const float w01 = vy0 && vx1 ? (1.f - wy) * wx         : 0.f;
        const float w10 = vy1 && vx0 ? wy * (1.f - wx)         : 0.f;
        const float w11 = vy1 && vx1 ? wy * wx                 : 0.f;
        const int i00 = (vy0 && vx0) ? y0 * W_ + x0 : 0;
        const int i01 = (vy0 && vx1) ? y0 * W_ + x1 : 0;
        const int i10 = (vy1 && vx0) ? y1 * W_ + x0 : 0;
        const int i11 = (vy1 && vx1) ? y1 * W_ + x1 : 0;

        const _Float16* xb = xg + (size_t)(b * DG_ + g) * HW_ * 4;
        const half4 p00 = *(const half4*)&xb[(size_t)i00 * 4];
        const half4 p01 = *(const half4*)&xb[(size_t)i01 * 4];
        const half4 p10 = *(const half4*)&xb[(size_t)i10 * 4];
        const half4 p11 = *(const half4*)&xb[(size_t)i11 * 4];

        half4 v4;
#pragma unroll
        for (int c = 0; c < CG_; ++c) {
            float v = w00 * (float)p00[c] + w01 * (float)p01[c]
                    + w10 * (float)p10[c] + w11 * (float)p11[c];
            v4[c] = (_Float16)(v * mA[g]);
        }
        rec[g] = v4;
    }

    // write slabs s = 2k (g 0..7) and 2k+1 (g 8..15): 64 B each, contiguous
    _Float16* r0 = &valh[((size_t)((2 * k) * B_ + b) * HW_ + pix) * 32];
    _Float16* r1 = &valh[((size_t)((2 * k + 1) * B_ + b) * HW_ + pix) * 32];
#pragma unroll
    for (int j = 0; j < 4; ++j) {
        half8 w0, w1;
#pragma unroll
        for (int c = 0; c < 4; ++c) {
            w0[c]     = rec[2 * j][c];
            w0[c + 4] = rec[2 * j + 1][c];
            w1[c]     = rec[8 + 2 * j][c];
            w1[c + 4] = rec[9 + 2 * j][c];
        }
        *(half8*)&r0[j * 8] = w0;
        *(half8*)&r1[j * 8] = w1;
    }
}

// ---------------------------------------------------------------------------
// Phase B: einsum via f16 MFMA. Wave = 16 px x 64 oc (mf=4).
// FULL A preload (72 KB), barrier-free 18-step loop, epilogue aliases A.
// ---------------------------------------------------------------------------
__global__ __launch_bounds__(256, 2) void einsum_mfma_k(
    const _Float16* __restrict__ valh, const _Float16* __restrict__ wkA,
    float* __restrict__ out)
{
    __shared__ __align__(16) _Float16 Smem[18 * 2048];  // 73728 B (union)
    float* Lds = (float*)Smem;                          // epilogue view

    const int tid  = threadIdx.x;
    const int lane = tid & 63;
    const int wv   = tid >> 6;
    const int l15  = lane & 15;
    const int quad = lane >> 4;

    const int pixg0 = blockIdx.x * 64 + wv * 16;    // global pixel (b*HW+pix)
    const int b     = pixg0 >> 14;
    const int pix0  = pixg0 & (HW_ - 1);

    const int sA = afrag_src(tid);

    // full preload: 18 slabs x 4 KB
#pragma unroll
    for (int s = 0; s < 18; ++s)
        gl_lds16(wkA + (size_t)s * 2048 + sA, Smem + s * 2048 + tid * 8);

    floatx4 acc[4];
#pragma unroll
    for (int mf = 0; mf < 4; ++mf)
        acc[mf] = (floatx4){0.f, 0.f, 0.f, 0.f};

    half8 Bf[2];
    Bf[0] = *(const half8*)&valh[((size_t)(0 * B_ + b) * HW_ + pix0 + l15) * 32 + quad * 8];
    __syncthreads();   // preload visible

#pragma unroll
    for (int s = 0; s < 18; ++s) {
        const int cur = s & 1, nxt = cur ^ 1;
        if (s < 17) {
            const int s1 = s + 1;
            Bf[nxt] = *(const half8*)&valh[
                ((size_t)(s1 * B_ + b) * HW_ + pix0 + l15) * 32 + quad * 8];
        }
        const _Float16* abase = Smem + s * 2048 + lane * 8;
#pragma unroll
        for (int mf = 0; mf < 4; ++mf) {
            const half8 afr = *(const half8*)&abase[mf * 512];
            acc[mf] = __builtin_amdgcn_mfma_f32_16x16x32_f16(afr, Bf[cur], acc[mf], 0, 0, 0);
        }
    }
    __syncthreads();   // all waves done reading A; safe to alias

    // ---- stage 64 oc x 64 px tile to LDS ----
    const int pxl = wv * 16 + l15;                  // 0..63 block-local pixel
#pragma unroll
    for (int mf = 0; mf < 4; ++mf)
#pragma unroll
        for (int reg = 0; reg < 4; ++reg)
            Lds[(mf * 16 + quad * 4 + reg) * 68 + pxl] = acc[mf][reg];
    __syncthreads();   // LDS read-only hereafter

    // ---- coalesced copy-out: 64 oc-rows x 64 px (16 float4 per row) ----
    const int pixb = blockIdx.x * 64 & (HW_ - 1);   // block-base pixel
#pragma unroll
    for (int it = 0; it < 4; ++it) {
        const int j4 = it * 256 + tid;
        const int r  = j4 >> 4;                     // oc 0..63
        const int c4 = j4 & 15;                     // float4 col
        float4 v;
        v.x = Lds[r * 68 + c4 * 4 + 0];
        v.y = Lds[r * 68 + c4 * 4 + 1];
        v.z = Lds[r * 68 + c4 * 4 + 2];
        v.w = Lds[r * 68 + c4 * 4 + 3];
        *(float4*)&out[((size_t)(b * C_ + r)) * HW_ + pixb + c4 * 4] = v;
    }
}

// ---------------------------------------------------------------------------
extern "C" void kernel_launch(void* const* d_in, const int* in_sizes, int n_in,
                              void* d_out, int out_size, void* d_ws, size_t ws_size,
                              hipStream_t stream)
{
    const float* x    = (const float*)d_in[0];
    const float* ef   = (const float*)d_in[1];
    const float* flow = (const float*)d_in[2];
    const float* w1   = (const float*)d_in[3];
    const float* b1   = (const float*)d_in[4];
    const float* w2   = (const float*)d_in[5];
    const float* b2   = (const float*)d_in[6];
    const float* w3   = (const float*)d_in[7];
    const float* b3   = (const float*)d_in[8];
    const float* wk   = (const float*)d_in[9];
    float* out = (float*)d_out;

    _Float16* omh  = (_Float16*)d_ws;
    _Float16* valh = omh + (size_t)B_ * OFFC_ * HW_;
    _Float16* ef_p = valh + (size_t)18 * B_ * HW_ * 32;
    _Float16* xg   = ef_p + (size_t)4 * B_ * HWP_ * 32;
    _Float16* h1p  = xg + (size_t)B_ * HW_ * 64;
    _Float16* h2p  = h1p + (size_t)2 * B_ * HWP_ * 32;
    _Float16* w1A  = h2p + (size_t)2 * B_ * HWP_ * 32;
    _Float16* w2A  = w1A + 64 * 128 * 9;
    _Float16* w3A  = w2A + 64 * 64 * 9;
    _Float16* wkA  = w3A + OFFC_ * 64 * 9;

    // ONE setup launch: all weight preps + both transposes + border zeroing
    // (replaces 6 kernels + 3 hipMemsetAsync; v11 launch-count 16 -> 6).
    setup_k<<<dim3(SR6), 256, 0, stream>>>(
        x, ef, w1, w2, w3, wk, w1A, w2A, w3A, wkA, ef_p, xg, h1p, h2p);

    conv1_mfma_k<<<dim3(B_ * H_ * 2), 256, 0, stream>>>(ef_p, w1A, b1, h1p);
    conv2_mfma_k<<<dim3(B_ * H_ * 2), 256, 0, stream>>>(h1p, w2A, b2, h2p);
    conv3_mfma_k<<<dim3(B_ * H_, 9), 256, 0, stream>>>(h2p, w3A, b3, flow, omh);

    gather_k<<<dim3(HW_ / 256, B_ * KK_), 256, 0, stream>>>(xg, omh, valh);
    einsum_mfma_k<<<dim3(B_ * HW_ / 64), 256, 0, stream>>>(valh, wkA, out);
}

// Round 12
// 182.053 us; speedup vs baseline: 1.2267x; 1.0397x over previous
//
#include <hip/hip_runtime.h>
#include <math.h>

// Problem constants (fixed by setup_inputs)
constexpr int B_   = 2;
constexpr int C_   = 64;
constexpr int H_   = 128;
constexpr int W_   = 128;
constexpr int HW_  = H_ * W_;
constexpr int DG_  = 16;   // deformable groups
constexpr int KK_  = 9;    // 3x3 taps
constexpr int CG_  = 4;    // channels per group = C/DG
constexpr int OFFC_ = 3 * KK_ * DG_;  // 432
constexpr int R_   = C_ * KK_;        // 576 reduction length
constexpr int WP_  = 130;             // padded width/height
constexpr int HWP_ = WP_ * WP_;       // 16900 padded pixels

typedef _Float16 half8 __attribute__((ext_vector_type(8)));  // 8 f16 = 4 VGPR
typedef _Float16 half4 __attribute__((ext_vector_type(4)));  // 8-byte load/store
typedef float floatx4 __attribute__((ext_vector_type(4)));   // MFMA acc

// Async global->LDS DMA, 16 B per lane. LDS dest is wave-uniform base +
// lane*16 (m104); every call site passes exactly that shape.
__device__ __forceinline__ void gl_lds16(const _Float16* g, _Float16* l)
{
    __builtin_amdgcn_global_load_lds(
        (const __attribute__((address_space(1))) void*)g,
        (__attribute__((address_space(3))) void*)l, 16, 0, 0);
}

// Fragment-major A staging: LDS chunk c (16 B) holds the data fragment
// (mf = c>>6) needs at lane (c&63): global f16 index within the K-slice.
__device__ __forceinline__ int afrag_src(int c)
{
    const int cmf = c >> 6, cq = (c >> 4) & 3, cl = c & 15;
    return (cmf * 16 + cl) * 32 + cq * 8;
}

// ---------------------------------------------------------------------------
// MERGED SETUP KERNEL: all weight preps + both layout transposes +
// border-only zeroing of padded buffers, dispatched by blockIdx.x range.
// ---------------------------------------------------------------------------
constexpr int SR0 = 288, SR1 = 432, SR2 = 1404, SR3 = 1548;
constexpr int SR4 = 1676, SR5 = 1804, SR6 = 1837;

__global__ __launch_bounds__(256) void setup_k(
    const float* __restrict__ x,  const float* __restrict__ ef,
    const float* __restrict__ w1, const float* __restrict__ w2,
    const float* __restrict__ w3, const float* __restrict__ wk,
    _Float16* __restrict__ w1A, _Float16* __restrict__ w2A,
    _Float16* __restrict__ w3A, _Float16* __restrict__ wkA,
    _Float16* __restrict__ ef_p, _Float16* __restrict__ xg,
    _Float16* __restrict__ h1p,  _Float16* __restrict__ h2p)
{
    const int bid = blockIdx.x;
    const int tid = threadIdx.x;

    if (bid < SR0) {                       // ---- prep w1A: OC=64, CIN=128
        constexpr int OC = 64, CH = 4;
        const int j = bid * 256 + tid;
        if (j >= 9 * CH * OC * 32) return;
        const int slab = j / (OC * 32);
        const int rem  = j - slab * (OC * 32);
        const int oc   = rem >> 5;
        const int jj   = rem & 31;
        const int t    = slab / CH;
        const int h    = slab - t * CH;
        const int ic   = h * 32 + jj;
        w1A[j] = (_Float16)w1[(size_t)oc * (128 * 9) + ic * 9 + t];
    } else if (bid < SR1) {                // ---- prep w2A: OC=64, CIN=64
        constexpr int OC = 64, CH = 2;
        const int j = (bid - SR0) * 256 + tid;
        if (j >= 9 * CH * OC * 32) return;
        const int slab = j / (OC * 32);
        const int rem  = j - slab * (OC * 32);
        const int oc   = rem >> 5;
        const int jj   = rem & 31;
        const int t    = slab / CH;
        const int h    = slab - t * CH;
        const int ic   = h * 32 + jj;
        w2A[j] = (_Float16)w2[(size_t)oc * (64 * 9) + ic * 9 + t];
    } else if (bid < SR2) {                // ---- prep w3A: OC=432, CIN=64
        constexpr int OC = OFFC_, CH = 2;
        const int j = (bid - SR1) * 256 + tid;
        if (j >= 9 * CH * OC * 32) return;
        const int slab = j / (OC * 32);
        const int rem  = j - slab * (OC * 32);
        const int oc   = rem >> 5;
        const int jj   = rem & 31;
        const int t    = slab / CH;
        const int h    = slab - t * CH;
        const int ic   = h * 32 + jj;
        w3A[j] = (_Float16)w3[(size_t)oc * (64 * 9) + ic * 9 + t];
    } else if (bid < SR3) {                // ---- prep wkA
        const int j = (bid - SR2) * 256 + tid;
        if (j >= 18 * 64 * 32) return;
        const int s   = j >> 11;
        const int rem = j & 2047;
        const int oc  = rem >> 5;
        const int jj  = rem & 31;
        const int k   = s >> 1;
        const int gc  = (s & 1) * 32 + jj;
        wkA[j] = (_Float16)wk[(size_t)oc * R_ + gc * 9 + k];
    } else if (bid < SR4) {                // ---- ef -> ef_p (padded slabs)
        const int lb  = bid - SR3;         // 0..127
        const int b   = lb >> 6;
        const int pix = (lb & 63) * 256 + tid;
        const int yp  = pix >> 7;
        const int xp  = pix & (W_ - 1);
        const float* ib = ef + (size_t)b * 128 * HW_ + pix;
#pragma unroll
        for (int c0 = 0; c0 < 128; c0 += 8) {
            half8 v;
#pragma unroll
            for (int j = 0; j < 8; ++j)
                v[j] = (_Float16)ib[(size_t)(c0 + j) * HW_];
            const int slab = c0 >> 5;
            *(half8*)&ef_p[((size_t)(slab * B_ + b) * HWP_
                            + (size_t)(yp + 1) * WP_ + (xp + 1)) * 32 + (c0 & 31)] = v;
        }
    } else if (bid < SR5) {                // ---- x -> xg (per-group planes)
        const int lb  = bid - SR4;         // 0..127
        const int b   = lb >> 6;
        const int pix = (lb & 63) * 256 + tid;
        const float* ib = x + (size_t)b * C_ * HW_ + pix;
#pragma unroll
        for (int g = 0; g < DG_; ++g) {
            half4 v;
#pragma unroll
            for (int c = 0; c < 4; ++c)
                v[c] = (_Float16)ib[(size_t)(g * 4 + c) * HW_];
            *(half4*)&xg[((size_t)(b * DG_ + g) * HW_ + pix) * 4] = v;
        }
    } else {                               // ---- border zero (16 planes)
        const int idx = (bid - SR5) * 256 + tid;   // plane*516 + p
        if (idx >= 16 * 516) return;
        const int plane = idx / 516;
        const int p     = idx - plane * 516;
        int yp, xp;
        if (p < 130)      { yp = 0;            xp = p; }
        else if (p < 260) { yp = 129;          xp = p - 130; }
        else if (p < 388) { yp = 1 + (p - 260); xp = 0; }
        else              { yp = 1 + (p - 388); xp = 129; }
        _Float16* base;
        if (plane < 8)       base = ef_p + (size_t)plane * HWP_ * 32;
        else if (plane < 12) base = h1p + (size_t)(plane - 8) * HWP_ * 32;
        else                 base = h2p + (size_t)(plane - 12) * HWP_ * 32;
        _Float16* dst = base + ((size_t)yp * WP_ + xp) * 32;
        const half8 z = (half8){0, 0, 0, 0, 0, 0, 0, 0};
#pragma unroll
        for (int j = 0; j < 4; ++j)
            *(half8*)&dst[j * 8] = z;
    }
}

// ---------------------------------------------------------------------------
// Conv1 (128 -> 64) via f16 MFMA. Wave tile = 64 oc x 16 px (mf=4).
// Split-K two-phase FULL preload; zero-VALU in-loop addressing.
// ---------------------------------------------------------------------------
__global__ __launch_bounds__(256, 2) void conv1_mfma_k(
    const _Float16* __restrict__ inp, const _Float16* __restrict__ wA,
    const float* __restrict__ bias, _Float16* __restrict__ outp)
{
    __shared__ __align__(16) _Float16 Asm[18 * 2048];   // 73728 B

    const int tid  = threadIdx.x;
    const int lane = tid & 63;
    const int wv   = tid >> 6;
    const int l15  = lane & 15;
    const int quad = lane >> 4;

    const int zx   = blockIdx.x;          // (b*H + y)*2 + half64
    const int row  = zx >> 1;
    const int b    = row >> 7;
    const int y    = row & 127;
    const int px0  = (zx & 1) * 64 + wv * 16;

    const int sA = afrag_src(tid);        // global f16 offset for my chunk

    // twelve {h 0..3, dy 0..2} B base pointers; per-step delta = immediate
    const _Float16* bb[12];
#pragma unroll
    for (int h = 0; h < 4; ++h)
#pragma unroll
        for (int dy = 0; dy < 3; ++dy)
            bb[h * 3 + dy] = inp + ((size_t)(h * B_ + b) * HWP_
                                    + (size_t)(y + dy) * WP_ + px0 + l15) * 32 + quad * 8;

    floatx4 acc[4];
#pragma unroll
    for (int mf = 0; mf < 4; ++mf)
        acc[mf] = (floatx4){0.f, 0.f, 0.f, 0.f};

    // ---- phase 0: preload slabs 0..17 ----
#pragma unroll
    for (int s = 0; s < 18; ++s)
        gl_lds16(wA + (size_t)s * 2048 + sA, Asm + s * 2048 + tid * 8);
    __syncthreads();   // staged + visible

    const _Float16* abase = Asm + lane * 8;
#pragma unroll
    for (int ks = 0; ks < 18; ++ks) {     // ks = t*4 + h  (CH=4)
        const int t = ks >> 2, h = ks & 3;
        const int dy = t / 3, dx = t % 3;
        const half8 bfr = *(const half8*)&bb[h * 3 + dy][dx * 32];
#pragma unroll
        for (int mf = 0; mf < 4; ++mf) {
            const half8 afr = *(const half8*)&abase[ks * 2048 + mf * 512];
            acc[mf] = __builtin_amdgcn_mfma_f32_16x16x32_f16(afr, bfr, acc[mf], 0, 0, 0);
        }
    }
    __syncthreads();   // all waves done reading phase-0 A

    // ---- phase 1: re-stage slabs 18..35 into the same LDS ----
#pragma unroll
    for (int s = 0; s < 18; ++s)
        gl_lds16(wA + (size_t)(18 + s) * 2048 + sA, Asm + s * 2048 + tid * 8);
    __syncthreads();   // staged + visible

#pragma unroll
    for (int ks = 18; ks < 36; ++ks) {
        const int t = ks >> 2, h = ks & 3;
        const int dy = t / 3, dx = t % 3;
        const half8 bfr = *(const half8*)&bb[h * 3 + dy][dx * 32];
#pragma unroll
        for (int mf = 0; mf < 4; ++mf) {
            const half8 afr = *(const half8*)&abase[(ks - 18) * 2048 + mf * 512];
            acc[mf] = __builtin_amdgcn_mfma_f32_16x16x32_f16(afr, bfr, acc[mf], 0, 0, 0);
        }
    }

    // epilogue: leaky ReLU, padded slab-split f16 store (8 B/lane x 4 tiles)
#pragma unroll
    for (int mf = 0; mf < 4; ++mf) {
        const int oc4 = mf * 16 + quad * 4;        // first of 4 output chans
        const float4 b4 = *(const float4*)&bias[oc4];
        half4 v4;
#pragma unroll
        for (int reg = 0; reg < 4; ++reg) {
            float r = acc[mf][reg] + ((const float*)&b4)[reg];
            r = (r >= 0.f) ? r : 0.1f * r;
            v4[reg] = (_Float16)r;
        }
        *(half4*)&outp[((size_t)((oc4 >> 5) * B_ + b) * HWP_
                        + (size_t)(y + 1) * WP_ + (px0 + l15 + 1)) * 32 + (oc4 & 31)] = v4;
    }
}

// ---------------------------------------------------------------------------
// Conv2 (64 -> 64) via f16 MFMA. Wave tile = 64 oc x 16 px (mf=4).
// FULL A preload (72 KB LDS), barrier-free 18-step K-loop, zero-VALU
// in-loop addressing (six {h,dy} base pointers, immediate offsets).
// ---------------------------------------------------------------------------
__global__ __launch_bounds__(256, 2) void conv2_mfma_k(
    const _Float16* __restrict__ inp, const _Float16* __restrict__ wA,
    const float* __restrict__ bias, _Float16* __restrict__ outp)
{
    __shared__ __align__(16) _Float16 Asm[18 * 2048];   // 73728 B

    const int tid  = threadIdx.x;
    const int lane = tid & 63;
    const int wv   = tid >> 6;
    const int l15  = lane & 15;
    const int quad = lane >> 4;

    const int zx   = blockIdx.x;          // (b*H + y)*2 + half64
    const int row  = zx >> 1;
    const int b    = row >> 7;
    const int y    = row & 127;
    const int px0  = (zx & 1) * 64 + wv * 16;

    const int sA = afrag_src(tid);

    // full preload: 18 slabs x 4 KB
#pragma unroll
    for (int s = 0; s < 18; ++s)
        gl_lds16(wA + (size_t)s * 2048 + sA, Asm + s * 2048 + tid * 8);

    // six {h, dy} B base pointers (all per-step variation is an immediate)
    const _Float16* bb[6];
#pragma unroll
    for (int h = 0; h < 2; ++h)
#pragma unroll
        for (int dy = 0; dy < 3; ++dy)
            bb[h * 3 + dy] = inp + ((size_t)(h * B_ + b) * HWP_
                                    + (size_t)(y + dy) * WP_ + px0 + l15) * 32 + quad * 8;

    floatx4 acc[4];
#pragma unroll
    for (int mf = 0; mf < 4; ++mf)
        acc[mf] = (floatx4){0.f, 0.f, 0.f, 0.f};

    __syncthreads();   // preload (all waves) visible

    const _Float16* abase = Asm + lane * 8;
#pragma unroll
    for (int ks = 0; ks < 18; ++ks) {     // ks = t*2 + h  (CH=2)
        const int t = ks >> 1, h = ks & 1;
        const int dy = t / 3, dx = t % 3;
        const half8 bfr = *(const half8*)&bb[h * 3 + dy][dx * 32];
#pragma unroll
        for (int mf = 0; mf < 4; ++mf) {
            const half8 afr = *(const half8*)&abase[ks * 2048 + mf * 512];
            acc[mf] = __builtin_amdgcn_mfma_f32_16x16x32_f16(afr, bfr, acc[mf], 0, 0, 0);
        }
    }

    // epilogue: leaky ReLU, padded slab-split f16 store
#pragma unroll
    for (int mf = 0; mf < 4; ++mf) {
        const int oc4 = mf * 16 + quad * 4;
        const float4 b4 = *(const float4*)&bias[oc4];
        half4 v4;
#pragma unroll
        for (int reg = 0; reg < 4; ++reg) {
            float r = acc[mf][reg] + ((const float*)&b4)[reg];
            r = (r >= 0.f) ? r : 0.1f * r;
            v4[reg] = (_Float16)r;
        }
        *(half4*)&outp[((size_t)((oc4 >> 5) * B_ + b) * HWP_
                        + (size_t)(y + 1) * WP_ + (px0 + l15 + 1)) * 32 + (oc4 & 31)] = v4;
    }
}

// ---------------------------------------------------------------------------
// Conv3 via f16 MFMA implicit GEMM.
// v12: TWO output rows per block (y0, y0+1). The 52-KB A-preload, Af17,
// and every in-loop A ds_read are shared by both rows -> per-px A cost
// halves; per K-step 7 loads feed 12 MFMAs (was 5:6); two independent
// B-chains add ILP. Grid (B*H/2, 9) = 1152 blocks.
// ---------------------------------------------------------------------------
__global__ __launch_bounds__(256, 2) void conv3_mfma_k(
    const _Float16* __restrict__ h2p, const _Float16* __restrict__ w3A,
    const float* __restrict__ bias, const float* __restrict__ flow,
    _Float16* __restrict__ omh)
{
    __shared__ __align__(16) _Float16 Smem[17 * 1536];   // 52224 B (union)
    _Float16* Lds = Smem;    // epilogue view: 2 rows x 48 x 132 f16 = 25344 B

    const int tid  = threadIdx.x;
    const int lane = tid & 63;
    const int wv   = tid >> 6;       // wave id 0..3
    const int l15  = lane & 15;
    const int quad = lane >> 4;

    const int row0 = blockIdx.x * 2; // even row
    const int b    = row0 >> 7;
    const int y0   = row0 & 127;
    const int m0   = blockIdx.y * 48; // oc tile base (0..384)
    const int px0  = wv * 32;

    // ---- full-K A preload, slices 0..16, fragment-major ----
#pragma unroll
    for (int r = 0; r < 13; ++r) {
        const int c = r * 256 + tid;          // global chunk id
        if (c < 17 * 192) {
            const int ks = c / 192;
            const int cl = c - ks * 192;      // chunk within slice
            const int cmf = cl >> 6, cq = (cl >> 4) & 3, ccl = cl & 15;
            gl_lds16(w3A + ((size_t)ks * OFFC_ + m0 + cmf * 16 + ccl) * 32 + cq * 8,
                     Smem + c * 8);
        }
    }

    // slice 17's A-fragments direct to registers (drained by the barrier)
    half8 Af17[3];
#pragma unroll
    for (int mf = 0; mf < 3; ++mf)
        Af17[mf] = *(const half8*)&w3A[
            ((size_t)17 * OFFC_ + m0 + mf * 16 + l15) * 32 + quad * 8];

    // eight {h, dyy 0..3} B base pointers; per-step variation = immediates
    const _Float16* bb2[8];
#pragma unroll
    for (int h = 0; h < 2; ++h)
#pragma unroll
        for (int dyy = 0; dyy < 4; ++dyy)
            bb2[h * 4 + dyy] = h2p + ((size_t)(h * B_ + b) * HWP_
                                      + (size_t)(y0 + dyy) * WP_ + px0 + l15) * 32 + quad * 8;

    floatx4 acc[3][2][2];   // [mf][nf][row]
#pragma unroll
    for (int mf = 0; mf < 3; ++mf)
#pragma unroll
        for (int nf = 0; nf < 2; ++nf)
#pragma unroll
            for (int rr = 0; rr < 2; ++rr)
                acc[mf][nf][rr] = (floatx4){0.f, 0.f, 0.f, 0.f};

    __syncthreads();   // preload visible (single drain before the loop)

    // ---- barrier-free K-loop; A ds_reads shared by both rows ----
    const _Float16* abase = Smem + lane * 8;
#pragma unroll
    for (int ks = 0; ks < 17; ++ks) {           // ks = t*2 + h, A from LDS
        const int t = ks >> 1, h = ks & 1;
        const int dy = t / 3, dx = t % 3;
        half8 bfr[2][2];                        // [row][nf]
#pragma unroll
        for (int rr = 0; rr < 2; ++rr)
#pragma unroll
            for (int nf = 0; nf < 2; ++nf)
                bfr[rr][nf] = *(const half8*)&bb2[h * 4 + dy + rr][(nf * 16 + dx) * 32];
#pragma unroll
        for (int mf = 0; mf < 3; ++mf) {
            const half8 afr = *(const half8*)&abase[ks * 1536 + mf * 512];
#pragma unroll
            for (int rr = 0; rr < 2; ++rr) {
                acc[mf][0][rr] = __builtin_amdgcn_mfma_f32_16x16x32_f16(afr, bfr[rr][0], acc[mf][0][rr], 0, 0, 0);
                acc[mf][1][rr] = __builtin_amdgcn_mfma_f32_16x16x32_f16(afr, bfr[rr][1], acc[mf][1][rr], 0, 0, 0);
            }
        }
    }
    {   // ks = 17: t=8 (dy=2, dx=2), h=1; A from registers
        half8 bfr[2][2];
#pragma unroll
        for (int rr = 0; rr < 2; ++rr)
#pragma unroll
            for (int nf = 0; nf < 2; ++nf)
                bfr[rr][nf] = *(const half8*)&bb2[4 + 2 + rr][(nf * 16 + 2) * 32];
#pragma unroll
        for (int mf = 0; mf < 3; ++mf)
#pragma unroll
            for (int rr = 0; rr < 2; ++rr) {
                acc[mf][0][rr] = __builtin_amdgcn_mfma_f32_16x16x32_f16(Af17[mf], bfr[rr][0], acc[mf][0][rr], 0, 0, 0);
                acc[mf][1][rr] = __builtin_amdgcn_mfma_f32_16x16x32_f16(Af17[mf], bfr[rr][1], acc[mf][1][rr], 0, 0, 0);
            }
    }
    __syncthreads();   // all waves done reading Smem; safe to alias Lds

    // ---- transform + stage to LDS (2 x 48 rows x 128 px, pad to 132) ----
    const bool is_off = (blockIdx.y < 6);     // block-uniform: m0 < 288
    float flY[2][2], flX[2][2];               // [row][nf]
#pragma unroll
    for (int rr = 0; rr < 2; ++rr)
#pragma unroll
        for (int nf = 0; nf < 2; ++nf) {
            const int px = px0 + nf * 16 + l15;
            if (is_off) {
                flY[rr][nf] = flow[(size_t)(b * 2 + 1) * HW_ + (y0 + rr) * W_ + px];
                flX[rr][nf] = flow[(size_t)(b * 2 + 0) * HW_ + (y0 + rr) * W_ + px];
            }
        }
#pragma unroll
    for (int mf = 0; mf < 3; ++mf) {
        const float4 b4 = *(const float4*)&bias[m0 + mf * 16 + quad * 4];
#pragma unroll
        for (int rr = 0; rr < 2; ++rr)
#pragma unroll
            for (int nf = 0; nf < 2; ++nf) {
                const int px = px0 + nf * 16 + l15;
#pragma unroll
                for (int reg = 0; reg < 4; ++reg) {
                    const int ocl = mf * 16 + quad * 4 + reg;   // 0..47
                    float val = acc[mf][nf][rr][reg] + ((const float*)&b4)[reg];
                    if (is_off) {                       // offset channels
                        const int slot = reg & 1;       // 0 = y, 1 = x
                        const float fl = slot ? flX[rr][nf] : flY[rr][nf];
                        const float e = __expf(2.f * val);      // tanh via exp
                        val = 10.f * (1.f - __fdividef(2.f, e + 1.f)) + fl;
                    } else {                            // mask channels: sigmoid
                        val = __fdividef(1.f, 1.f + __expf(-val));
                    }
                    Lds[rr * 6336 + ocl * 132 + px] = (_Float16)val;
                }
            }
    }
    __syncthreads();   // LDS read-only hereafter

    // ---- contiguous f16 copy-out: 2 rows x 48 plane-rows x 128 px ----
#pragma unroll
    for (int rr = 0; rr < 2; ++rr)
#pragma unroll
        for (int it = 0; it < 6; ++it) {
            const int j4 = it * 256 + tid;
            const int r  = j4 >> 5;          // 0..47
            const int c4 = j4 & 31;          // half4 col
            const int oc = m0 + r;
            int g, k, slot;
            if (oc < 2 * DG_ * KK_) {
                g = oc / 18;
                const int rem = oc - g * 18;
                k = rem >> 1;
                slot = rem & 1;
            } else {
                const int c = oc - 2 * DG_ * KK_;
                g = c / 9;
                k = c - g * 9;
                slot = 2;
            }
            const half4 hv = *(const half4*)&Lds[rr * 6336 + r * 132 + c4 * 4];
            *(half4*)&omh[((size_t)((b * DG_ * KK_ + g * KK_ + k) * 3 + slot)) * HW_
                          + (y0 + rr) * W_ + c4 * 4] = hv;
        }
}

// ---------------------------------------------------------------------------
// Phase A: bilinear gather, PIXEL-MAJOR lanes; omh loads burst-hoisted.
// ---------------------------------------------------------------------------
__global__ __launch_bounds__(256, 2) void gather_k(
    const _Float16* __restrict__ xg, const _Float16* __restrict__ omh,
    _Float16* __restrict__ valh)
{
    const int tid = threadIdx.x;
    const int pix = blockIdx.x * 256 + tid;
    const int zy  = blockIdx.y;               // b*9 + k
    const int b   = zy / KK_;
    const int k   = zy - b * KK_;
    const int yp  = pix >> 7;
    const int xp  = pix & (W_ - 1);
    const float fy = (float)(yp + (k / 3) - 1);
    const float fx = (float)(xp + (k % 3) - 1);

    // burst-load all offsets/masks (static indices; 48 loads in flight)
    float oyA[16], oxA[16], mA[16];
#pragma unroll
    for (int g = 0; g < DG_; ++g) {
        const size_t obase = ((size_t)((b * DG_ + g) * KK_ + k) * 3) * HW_ + pix;
        oyA[g] = (float)omh[obase];
        oxA[g] = (float)omh[obase + HW_];
        mA[g]  = (float)omh[obase + 2 * HW_];
    }

    half4 rec[16];
#pragma unroll
    for (int g = 0; g < DG_; ++g) {
        const float py = fy + oyA[g];
        const float px = fx + oxA[g];
        const float y0f = floorf(py);
        const float x0f = floorf(px);
        const float wy = py - y0f;
        const float wx = px - x0f;
        const int y0 = (int)y0f, x0 = (int)x0f;
        const int y1 = y0 + 1,  x1 = x0 + 1;
        const bool vy0 = ((unsigned)y0 < (unsigned)H_);
        const bool vy1 = ((unsigned)y1 < (unsigned)H_);
        const bool vx0 = ((unsigned)x0 < (unsigned)W_);
        const bool vx1 = ((unsigned)x1 < (unsigned)W_);
        const float w00 = vy0 && vx0 ? (1.f - wy) * (1.f - wx) : 0.f;
        const float w01 = vy0 && vx1 ? (1.f - wy) * wx         : 0.f;
        const float w10 = vy1 && vx0 ? wy * (1.f - wx)         : 0.f;
        const float w11 = vy1 && vx1 ? wy * wx                 : 0.f;
        const int i00 = (vy0 && vx0) ? y0 * W_ + x0 : 0;
        const int i01 = (vy0 && vx1) ? y0 * W_ + x1 : 0;
        const int i10 = (vy1 && vx0) ? y1 * W_ + x0 : 0;
        const int i11 = (vy1 && vx1) ? y1 * W_ + x1 : 0;

        const _Float16* xb = xg + (size_t)(b * DG_ + g) * HW_ * 4;
        const half4 p00 = *(const half4*)&xb[(size_t)i00 * 4];
        const half4 p01 = *(const half4*)&xb[(size_t)i01 * 4];
        const half4 p10 = *(const half4*)&xb[(size_t)i10 * 4];
        const half4 p11 = *(const half4*)&xb[(size_t)i11 * 4];

        half4 v4;
#pragma unroll
        for (int c = 0; c < CG_; ++c) {
            float v = w00 * (float)p00[c] + w01 * (float)p01[c]
                    + w10 * (float)p10[c] + w11 * (float)p11[c];
            v4[c] = (_Float16)(v * mA[g]);
        }
        rec[g] = v4;
    }

    // write slabs s = 2k (g 0..7) and 2k+1 (g 8..15): 64 B each, contiguous
    _Float16* r0 = &valh[((size_t)((2 * k) * B_ + b) * HW_ + pix) * 32];
    _Float16* r1 = &valh[((size_t)((2 * k + 1) * B_ + b) * HW_ + pix) * 32];
#pragma unroll
    for (int j = 0; j < 4; ++j) {
        half8 w0, w1;
#pragma unroll
        for (int c = 0; c < 4; ++c) {
            w0[c]     = rec[2 * j][c];
            w0[c + 4] = rec[2 * j + 1][c];
            w1[c]     = rec[8 + 2 * j][c];
            w1[c + 4] = rec[9 + 2 * j][c];
        }
        *(half8*)&r0[j * 8] = w0;
        *(half8*)&r1[j * 8] = w1;
    }
}

// ---------------------------------------------------------------------------
// Phase B: einsum via f16 MFMA. Wave = 16 px x 64 oc (mf=4).
// FULL A preload (72 KB), barrier-free 18-step loop, epilogue aliases A.
// ---------------------------------------------------------------------------
__global__ __launch_bounds__(256, 2) void einsum_mfma_k(
    const _Float16* __restrict__ valh, const _Float16* __restrict__ wkA,
    float* __restrict__ out)
{
    __shared__ __align__(16) _Float16 Smem[18 * 2048];  // 73728 B (union)
    float* Lds = (float*)Smem;                          // epilogue view

    const int tid  = threadIdx.x;
    const int lane = tid & 63;
    const int wv   = tid >> 6;
    const int l15  = lane & 15;
    const int quad = lane >> 4;

    const int pixg0 = blockIdx.x * 64 + wv * 16;    // global pixel (b*HW+pix)
    const int b     = pixg0 >> 14;
    const int pix0  = pixg0 & (HW_ - 1);

    const int sA = afrag_src(tid);

    // full preload: 18 slabs x 4 KB
#pragma unroll
    for (int s = 0; s < 18; ++s)
        gl_lds16(wkA + (size_t)s * 2048 + sA, Smem + s * 2048 + tid * 8);

    floatx4 acc[4];
#pragma unroll
    for (int mf = 0; mf < 4; ++mf)
        acc[mf] = (floatx4){0.f, 0.f, 0.f, 0.f};

    half8 Bf[2];
    Bf[0] = *(const half8*)&valh[((size_t)(0 * B_ + b) * HW_ + pix0 + l15) * 32 + quad * 8];
    __syncthreads();   // preload visible

#pragma unroll
    for (int s = 0; s < 18; ++s) {
        const int cur = s & 1, nxt = cur ^ 1;
        if (s < 17) {
            const int s1 = s + 1;
            Bf[nxt] = *(const half8*)&valh[
                ((size_t)(s1 * B_ + b) * HW_ + pix0 + l15) * 32 + quad * 8];
        }
        const _Float16* abase = Smem + s * 2048 + lane * 8;
#pragma unroll
        for (int mf = 0; mf < 4; ++mf) {
            const half8 afr = *(const half8*)&abase[mf * 512];
            acc[mf] = __builtin_amdgcn_mfma_f32_16x16x32_f16(afr, Bf[cur], acc[mf], 0, 0, 0);
        }
    }
    __syncthreads();   // all waves done reading A; safe to alias

    // ---- stage 64 oc x 64 px tile to LDS ----
    const int pxl = wv * 16 + l15;                  // 0..63 block-local pixel
#pragma unroll
    for (int mf = 0; mf < 4; ++mf)
#pragma unroll
        for (int reg = 0; reg < 4; ++reg)
            Lds[(mf * 16 + quad * 4 + reg) * 68 + pxl] = acc[mf][reg];
    __syncthreads();   // LDS read-only hereafter

    // ---- coalesced copy-out: 64 oc-rows x 64 px (16 float4 per row) ----
    const int pixb = blockIdx.x * 64 & (HW_ - 1);   // block-base pixel
#pragma unroll
    for (int it = 0; it < 4; ++it) {
        const int j4 = it * 256 + tid;
        const int r  = j4 >> 4;                     // oc 0..63
        const int c4 = j4 & 15;                     // float4 col
        float4 v;
        v.x = Lds[r * 68 + c4 * 4 + 0];
        v.y = Lds[r * 68 + c4 * 4 + 1];
        v.z = Lds[r * 68 + c4 * 4 + 2];
        v.w = Lds[r * 68 + c4 * 4 + 3];
        *(float4*)&out[((size_t)(b * C_ + r)) * HW_ + pixb + c4 * 4] = v;
    }
}

// ---------------------------------------------------------------------------
extern "C" void kernel_launch(void* const* d_in, const int* in_sizes, int n_in,
                              void* d_out, int out_size, void* d_ws, size_t ws_size,
                              hipStream_t stream)
{
    const float* x    = (const float*)d_in[0];
    const float* ef   = (const float*)d_in[1];
    const float* flow = (const float*)d_in[2];
    const float* w1   = (const float*)d_in[3];
    const float* b1   = (const float*)d_in[4];
    const float* w2   = (const float*)d_in[5];
    const float* b2   = (const float*)d_in[6];
    const float* w3   = (const float*)d_in[7];
    const float* b3   = (const float*)d_in[8];
    const float* wk   = (const float*)d_in[9];
    float* out = (float*)d_out;

    _Float16* omh  = (_Float16*)d_ws;
    _Float16* valh = omh + (size_t)B_ * OFFC_ * HW_;
    _Float16* ef_p = valh + (size_t)18 * B_ * HW_ * 32;
    _Float16* xg   = ef_p + (size_t)4 * B_ * HWP_ * 32;
    _Float16* h1p  = xg + (size_t)B_ * HW_ * 64;
    _Float16* h2p  = h1p + (size_t)2 * B_ * HWP_ * 32;
    _Float16* w1A  = h2p + (size_t)2 * B_ * HWP_ * 32;
    _Float16* w2A  = w1A + 64 * 128 * 9;
    _Float16* w3A  = w2A + 64 * 64 * 9;
    _Float16* wkA  = w3A + OFFC_ * 64 * 9;

    // ONE setup launch: all weight preps + both transposes + border zeroing
    setup_k<<<dim3(SR6), 256, 0, stream>>>(
        x, ef, w1, w2, w3, wk, w1A, w2A, w3A, wkA, ef_p, xg, h1p, h2p);

    conv1_mfma_k<<<dim3(B_ * H_ * 2), 256, 0, stream>>>(ef_p, w1A, b1, h1p);
    conv2_mfma_k<<<dim3(B_ * H_ * 2), 256, 0, stream>>>(h1p, w2A, b2, h2p);
    conv3_mfma_k<<<dim3(B_ * H_ / 2, 9), 256, 0, stream>>>(h2p, w3A, b3, flow, omh);

    gather_k<<<dim3(HW_ / 256, B_ * KK_), 256, 0, stream>>>(xg, omh, valh);
    einsum_mfma_k<<<dim3(B_ * HW_ / 64), 256, 0, stream>>>(valh, wkA, out);
}